// Round 1
// baseline (6285.764 us; speedup 1.0000x reference)
//
#include <hip/hip_runtime.h>
#include <math.h>

#define ALPHA 0.2f

constexpr int FEATS = 256;   // NFEATS == NHIDS
constexpr int HEADS = 8;
constexpr int GRUC = 768;    // 3 * NHIDS

// ---------- helpers ----------
__device__ __forceinline__ int f2o(float f) {
    int i = __float_as_int(f);
    return i >= 0 ? i : i ^ 0x7FFFFFFF;
}
__device__ __forceinline__ float o2f(int i) {
    return __int_as_float(i >= 0 ? i : i ^ 0x7FFFFFFF);
}
__device__ __forceinline__ float edge_e(const float* __restrict__ es,
                                        const float* __restrict__ ed,
                                        const float* __restrict__ ab,
                                        int s, int d, int h) {
    float e = es[s * 8 + h] + ed[d * 8 + h] + ab[h];
    return e > 0.f ? e : ALPHA * e;
}

// ---------- fp32 tiled GEMM ----------
// BMODE 0: C[n,j] = sum_f A[n,f] * W[h(j), f, d(j)] + bias[j]   (W: [H, K, 32])
// BMODE 1: C[n,j] = sum_k A[n,k] * W[j, k] + bias[j]            (W: [Ncols, K])
template <int BMODE>
__global__ __launch_bounds__(256) void gemm_f32(
    const float* __restrict__ A, const float* __restrict__ B,
    const float* __restrict__ bias, float* __restrict__ C,
    int M, int Ncols, int K) {
    __shared__ float As[32][68];
    __shared__ float Bs[32][68];
    const int bm = blockIdx.x * 64;
    const int bn = blockIdx.y * 64;
    const int tid = threadIdx.x;
    const int tn = tid & 15, tm = tid >> 4;
    float acc[4][4] = {};
    for (int kb = 0; kb < K; kb += 32) {
        // A tile: 64 rows x 32 k
#pragma unroll
        for (int l = 0; l < 2; ++l) {
            int i = tid + l * 256;
            int row = i >> 3;
            int c4 = (i & 7) * 4;
            float4 v = make_float4(0.f, 0.f, 0.f, 0.f);
            int gr = bm + row;
            if (gr < M) v = *(const float4*)(A + (size_t)gr * K + kb + c4);
            As[c4 + 0][row] = v.x; As[c4 + 1][row] = v.y;
            As[c4 + 2][row] = v.z; As[c4 + 3][row] = v.w;
        }
        // B tile: 32 k x 64 j
        if (BMODE == 0) {
#pragma unroll
            for (int l = 0; l < 2; ++l) {
                int i = tid + l * 256;
                int k = i >> 4;
                int sub = i & 15;
                int j = (sub >> 3) * 32 + (sub & 7) * 4;
                int head = (bn + j) >> 5;
                int d = (bn + j) & 31;
                float4 v = *(const float4*)(B + (size_t)head * K * 32 +
                                            (size_t)(kb + k) * 32 + d);
                *(float4*)&Bs[k][j] = v;
            }
        } else {
#pragma unroll
            for (int l = 0; l < 2; ++l) {
                int i = tid + l * 256;
                int j = i >> 3;
                int c4 = (i & 7) * 4;
                float4 v = *(const float4*)(B + (size_t)(bn + j) * K + kb + c4);
                Bs[c4 + 0][j] = v.x; Bs[c4 + 1][j] = v.y;
                Bs[c4 + 2][j] = v.z; Bs[c4 + 3][j] = v.w;
            }
        }
        __syncthreads();
#pragma unroll
        for (int k = 0; k < 32; ++k) {
            float a[4], b[4];
            *(float4*)a = *(const float4*)&As[k][tm * 4];
            *(float4*)b = *(const float4*)&Bs[k][tn * 4];
#pragma unroll
            for (int x = 0; x < 4; ++x)
#pragma unroll
                for (int y = 0; y < 4; ++y) acc[x][y] += a[x] * b[y];
        }
        __syncthreads();
    }
#pragma unroll
    for (int x = 0; x < 4; ++x) {
        int gr = bm + tm * 4 + x;
        if (gr < M) {
#pragma unroll
            for (int y = 0; y < 4; ++y) {
                int gc = bn + tn * 4 + y;
                C[(size_t)gr * Ncols + gc] = acc[x][y] + bias[gc];
            }
        }
    }
}

// ---------- es/ed per (node, head) ----------
template <int DO_S, int DO_D>
__global__ void esed_kernel(const float* __restrict__ Wh,
                            const float* __restrict__ a_s,
                            const float* __restrict__ a_d,
                            float* __restrict__ es, float* __restrict__ ed,
                            int n) {
    int idx = blockIdx.x * blockDim.x + threadIdx.x;
    if (idx >= n * 8) return;
    int node = idx >> 3, h = idx & 7;
    const float* row = Wh + (size_t)node * FEATS + h * 32;
    float ss = 0.f, dd = 0.f;
#pragma unroll
    for (int i = 0; i < 8; ++i) {
        float4 v = *(const float4*)(row + i * 4);
        if (DO_S) {
            float4 w = *(const float4*)(a_s + h * 32 + i * 4);
            ss += v.x * w.x + v.y * w.y + v.z * w.z + v.w * w.w;
        }
        if (DO_D) {
            float4 w = *(const float4*)(a_d + h * 32 + i * 4);
            dd += v.x * w.x + v.y * w.y + v.z * w.z + v.w * w.w;
        }
    }
    if (DO_S) es[idx] = ss;
    if (DO_D) ed[idx] = dd;
}

__global__ void init_m_kernel(int* __restrict__ m, int n8) {
    int i = blockIdx.x * blockDim.x + threadIdx.x;
    if (i < n8) m[i] = (int)0x807FFFFF;  // f2o(-inf)
}

__global__ void edge_max_kernel(const int* __restrict__ src, const int* __restrict__ dst,
                                const float* __restrict__ es, const float* __restrict__ ed,
                                const float* __restrict__ ab, int* __restrict__ m,
                                int e_cnt) {
    int i = blockIdx.x * blockDim.x + threadIdx.x;
    if (i >= e_cnt * 8) return;
    int eid = i >> 3, h = i & 7;
    int s = src[eid], d = dst[eid];
    float e = edge_e(es, ed, ab, s, d, h);
    atomicMax(&m[d * 8 + h], f2o(e));
}

__global__ void decode_m_kernel(int* __restrict__ m, int n8) {
    int i = blockIdx.x * blockDim.x + threadIdx.x;
    if (i < n8) ((float*)m)[i] = o2f(m[i]);
}

__global__ void edge_sum_kernel(const int* __restrict__ src, const int* __restrict__ dst,
                                const float* __restrict__ es, const float* __restrict__ ed,
                                const float* __restrict__ ab, const float* __restrict__ mf,
                                float* __restrict__ sden, int e_cnt) {
    int i = blockIdx.x * blockDim.x + threadIdx.x;
    if (i >= e_cnt * 8) return;
    int eid = i >> 3, h = i & 7;
    int s = src[eid], d = dst[eid];
    float e = edge_e(es, ed, ab, s, d, h);
    atomicAdd(&sden[d * 8 + h], expf(e - mf[d * 8 + h]));
}

__global__ void edge_scatter_kernel(const int* __restrict__ src, const int* __restrict__ dst,
                                    const float* __restrict__ es, const float* __restrict__ ed,
                                    const float* __restrict__ ab, const float* __restrict__ mf,
                                    const float* __restrict__ sden,
                                    const float* __restrict__ Wh,
                                    float* __restrict__ out, float coeff, int e_cnt) {
    long long i = (long long)blockIdx.x * blockDim.x + threadIdx.x;
    if (i >= (long long)e_cnt * 64) return;
    int eid = (int)(i >> 6);
    int lane = (int)(i & 63);
    int o = lane * 4;
    int h = o >> 5;
    int s = src[eid], d = dst[eid];
    float e = edge_e(es, ed, ab, s, d, h);
    float att = expf(e - mf[d * 8 + h]) / sden[d * 8 + h];
    float w = coeff * att;
    float4 v = *(const float4*)(Wh + (size_t)s * FEATS + o);
    float* op = out + (size_t)d * FEATS + o;
    atomicAdd(op + 0, w * v.x);
    atomicAdd(op + 1, w * v.y);
    atomicAdd(op + 2, w * v.z);
    atomicAdd(op + 3, w * v.w);
}

// ---------- GRU elementwise ----------
__global__ void gru_ew_kernel(const float* __restrict__ gi, const float* __restrict__ gh,
                              const float* __restrict__ hmix, float* __restrict__ out,
                              int rows, int row0) {
    int i = blockIdx.x * blockDim.x + threadIdx.x;
    if (i >= rows * FEATS) return;
    int r = i >> 8, j = i & 255;
    const float* gir = gi + (size_t)r * GRUC;
    const float* ghr = gh + (size_t)r * GRUC;
    float ir = gir[j], iz = gir[256 + j], in_ = gir[512 + j];
    float hr = ghr[j], hz = ghr[256 + j], hn = ghr[512 + j];
    float rr = 1.f / (1.f + expf(-(ir + hr)));
    float zz = 1.f / (1.f + expf(-(iz + hz)));
    float nn = tanhf(in_ + rr * hn);
    float hm = hmix[(size_t)(row0 + r) * FEATS + j];
    out[(size_t)(row0 + r) * FEATS + j] = (1.f - zz) * nn + zz * hm;
}

// ---------- launch ----------
extern "C" void kernel_launch(void* const* d_in, const int* in_sizes, int n_in,
                              void* d_out, int out_size, void* d_ws, size_t ws_size,
                              hipStream_t stream) {
    const float* h        = (const float*)d_in[0];
    const float* hp_cnt   = (const float*)d_in[1];
    const float* hp_sup   = (const float*)d_in[2];
    const float* hp_dst   = (const float*)d_in[3];
    const float* W_gat    = (const float*)d_in[4];
    const float* b_gat    = (const float*)d_in[5];
    const float* as_gat   = (const float*)d_in[6];
    const float* ad_gat   = (const float*)d_in[7];
    const float* ab_gat   = (const float*)d_in[8];
    const float* W_x      = (const float*)d_in[9];
    const float* b_x      = (const float*)d_in[10];
    const float* as_x     = (const float*)d_in[11];
    const float* ad_x     = (const float*)d_in[12];
    const float* ab_x     = (const float*)d_in[13];
    const float* W_ih     = (const float*)d_in[14];
    const float* W_hh     = (const float*)d_in[15];
    const float* b_ih     = (const float*)d_in[16];
    const float* b_hh     = (const float*)d_in[17];
    const int* e_src      = (const int*)d_in[18];
    const int* e_dst      = (const int*)d_in[19];
    const int* ec_src     = (const int*)d_in[20];
    const int* ec_dst     = (const int*)d_in[21];
    const int* es_src     = (const int*)d_in[22];
    const int* es_dst     = (const int*)d_in[23];

    const int N = in_sizes[0] / FEATS;
    const int E = in_sizes[18];
    const int N8 = N * HEADS;

    const size_t NB = (size_t)N * FEATS * sizeof(float);
    const size_t N8B = (size_t)N8 * sizeof(float);
    char* ws = (char*)d_ws;
    float* bufA = (float*)ws;                 // Wh (src side) / gi chunk
    float* bufB = (float*)(ws + NB);          // Wh (dst side) / gh chunk
    float* hmix = (float*)(ws + 2 * NB);
    float* esb  = (float*)(ws + 3 * NB);
    float* edb  = (float*)(ws + 3 * NB + N8B);
    int*   mb   = (int*)  (ws + 3 * NB + 2 * N8B);
    float* sden = (float*)(ws + 3 * NB + 3 * N8B);
    float* xbuf = (float*)d_out;  // x lives in d_out; overwritten per-chunk by GRU

    const dim3 blk(256);
    const int gM = (N + 63) / 64;
    const dim3 gProj(gM, FEATS / 64);
    const int gN8 = (N8 + 255) / 256;
    const int gE8 = (E * 8 + 255) / 256;
    const int gE64 = (int)(((long long)E * 64 + 255) / 256);

    auto run_edges = [&](const int* src, const int* dst, const float* ab,
                         const float* WhS, float* out, float coeff) {
        hipMemsetAsync(sden, 0, N8B, stream);
        init_m_kernel<<<gN8, blk, 0, stream>>>(mb, N8);
        edge_max_kernel<<<gE8, blk, 0, stream>>>(src, dst, esb, edb, ab, mb, E);
        decode_m_kernel<<<gN8, blk, 0, stream>>>(mb, N8);
        edge_sum_kernel<<<gE8, blk, 0, stream>>>(src, dst, esb, edb, ab, (float*)mb, sden, E);
        edge_scatter_kernel<<<gE64, blk, 0, stream>>>(src, dst, esb, edb, ab, (float*)mb,
                                                      sden, WhS, out, coeff, E);
    };

    // ---- GAT1: intra-turn on h ----
    hipMemsetAsync(xbuf, 0, NB, stream);
    gemm_f32<0><<<gProj, blk, 0, stream>>>(h, W_gat, b_gat, bufA, N, FEATS, FEATS);
    esed_kernel<1, 1><<<gN8, blk, 0, stream>>>(bufA, as_gat, ad_gat, esb, edb, N);
    run_edges(e_src, e_dst, ab_gat, bufA, xbuf, 1.0f);

    // ---- GAT2: counter (hp_counter -> hp_dst) ----
    hipMemsetAsync(hmix, 0, NB, stream);
    gemm_f32<0><<<gProj, blk, 0, stream>>>(hp_cnt, W_x, b_x, bufA, N, FEATS, FEATS);
    gemm_f32<0><<<gProj, blk, 0, stream>>>(hp_dst, W_x, b_x, bufB, N, FEATS, FEATS);
    esed_kernel<1, 0><<<gN8, blk, 0, stream>>>(bufA, as_x, nullptr, esb, nullptr, N);
    esed_kernel<0, 1><<<gN8, blk, 0, stream>>>(bufB, nullptr, ad_x, nullptr, edb, N);
    run_edges(ec_src, ec_dst, ab_x, bufA, hmix, 0.5f);

    // ---- GAT3: support (hp_support -> hp_dst); ed unchanged ----
    gemm_f32<0><<<gProj, blk, 0, stream>>>(hp_sup, W_x, b_x, bufA, N, FEATS, FEATS);
    esed_kernel<1, 0><<<gN8, blk, 0, stream>>>(bufA, as_x, nullptr, esb, nullptr, N);
    run_edges(es_src, es_dst, ab_x, bufA, hmix, 0.5f);

    // ---- GRU, chunked so gi/gh fit in bufA/bufB ----
    const int CH = 16384;
    for (int row0 = 0; row0 < N; row0 += CH) {
        int rows = min(CH, N - row0);
        dim3 gG((rows + 63) / 64, GRUC / 64);
        gemm_f32<1><<<gG, blk, 0, stream>>>(xbuf + (size_t)row0 * FEATS, W_ih, b_ih,
                                            bufA, rows, GRUC, FEATS);
        gemm_f32<1><<<gG, blk, 0, stream>>>(hmix + (size_t)row0 * FEATS, W_hh, b_hh,
                                            bufB, rows, GRUC, FEATS);
        int gEw = (rows * FEATS + 255) / 256;
        gru_ew_kernel<<<gEw, blk, 0, stream>>>(bufA, bufB, hmix, (float*)d_out, rows, row0);
    }
}

// Round 2
// 1613.788 us; speedup vs baseline: 3.8950x; 3.8950x over previous
//
#include <hip/hip_runtime.h>
#include <math.h>

#define ALPHA 0.2f

constexpr int FEATS = 256;   // NFEATS == NHIDS
constexpr int HEADS = 8;
constexpr int GRUC = 768;    // 3 * NHIDS

// ---------- fp32 tiled GEMM ----------
// BMODE 0: C[n,j] = sum_f A[n,f] * W[h(j), f, d(j)] + bias[j]   (W: [H, K, 32])
// BMODE 1: C[n,j] = sum_k A[n,k] * W[j, k] + bias[j]            (W: [Ncols, K])
template <int BMODE>
__global__ __launch_bounds__(256) void gemm_f32(
    const float* __restrict__ A, const float* __restrict__ B,
    const float* __restrict__ bias, float* __restrict__ C,
    int M, int Ncols, int K) {
    __shared__ float As[32][68];
    __shared__ float Bs[32][68];
    const int bm = blockIdx.x * 64;
    const int bn = blockIdx.y * 64;
    const int tid = threadIdx.x;
    const int tn = tid & 15, tm = tid >> 4;
    float acc[4][4] = {};
    for (int kb = 0; kb < K; kb += 32) {
#pragma unroll
        for (int l = 0; l < 2; ++l) {
            int i = tid + l * 256;
            int row = i >> 3;
            int c4 = (i & 7) * 4;
            float4 v = make_float4(0.f, 0.f, 0.f, 0.f);
            int gr = bm + row;
            if (gr < M) v = *(const float4*)(A + (size_t)gr * K + kb + c4);
            As[c4 + 0][row] = v.x; As[c4 + 1][row] = v.y;
            As[c4 + 2][row] = v.z; As[c4 + 3][row] = v.w;
        }
        if (BMODE == 0) {
#pragma unroll
            for (int l = 0; l < 2; ++l) {
                int i = tid + l * 256;
                int k = i >> 4;
                int sub = i & 15;
                int j = (sub >> 3) * 32 + (sub & 7) * 4;
                int head = (bn + j) >> 5;
                int d = (bn + j) & 31;
                float4 v = *(const float4*)(B + (size_t)head * K * 32 +
                                            (size_t)(kb + k) * 32 + d);
                *(float4*)&Bs[k][j] = v;
            }
        } else {
#pragma unroll
            for (int l = 0; l < 2; ++l) {
                int i = tid + l * 256;
                int j = i >> 3;
                int c4 = (i & 7) * 4;
                float4 v = *(const float4*)(B + (size_t)(bn + j) * K + kb + c4);
                Bs[c4 + 0][j] = v.x; Bs[c4 + 1][j] = v.y;
                Bs[c4 + 2][j] = v.z; Bs[c4 + 3][j] = v.w;
            }
        }
        __syncthreads();
#pragma unroll
        for (int k = 0; k < 32; ++k) {
            float a[4], b[4];
            *(float4*)a = *(const float4*)&As[k][tm * 4];
            *(float4*)b = *(const float4*)&Bs[k][tn * 4];
#pragma unroll
            for (int x = 0; x < 4; ++x)
#pragma unroll
                for (int y = 0; y < 4; ++y) acc[x][y] += a[x] * b[y];
        }
        __syncthreads();
    }
#pragma unroll
    for (int x = 0; x < 4; ++x) {
        int gr = bm + tm * 4 + x;
        if (gr < M) {
#pragma unroll
            for (int y = 0; y < 4; ++y) {
                int gc = bn + tn * 4 + y;
                C[(size_t)gr * Ncols + gc] = acc[x][y] + bias[gc];
            }
        }
    }
}

// ---------- es/ed per (node, head) ----------
template <int DO_S, int DO_D>
__global__ void esed_kernel(const float* __restrict__ Wh,
                            const float* __restrict__ a_s,
                            const float* __restrict__ a_d,
                            float* __restrict__ es, float* __restrict__ ed,
                            int n) {
    int idx = blockIdx.x * blockDim.x + threadIdx.x;
    if (idx >= n * 8) return;
    int node = idx >> 3, h = idx & 7;
    const float* row = Wh + (size_t)node * FEATS + h * 32;
    float ss = 0.f, dd = 0.f;
#pragma unroll
    for (int i = 0; i < 8; ++i) {
        float4 v = *(const float4*)(row + i * 4);
        if (DO_S) {
            float4 w = *(const float4*)(a_s + h * 32 + i * 4);
            ss += v.x * w.x + v.y * w.y + v.z * w.z + v.w * w.w;
        }
        if (DO_D) {
            float4 w = *(const float4*)(a_d + h * 32 + i * 4);
            dd += v.x * w.x + v.y * w.y + v.z * w.z + v.w * w.w;
        }
    }
    if (DO_S) es[idx] = ss;
    if (DO_D) ed[idx] = dd;
}

// ---------- CSR build ----------
__global__ void count_kernel(const int* __restrict__ dst, int* __restrict__ cnt,
                             int e_cnt) {
    int e = blockIdx.x * blockDim.x + threadIdx.x;
    if (e < e_cnt) atomicAdd(&cnt[dst[e]], 1);
}

__global__ void scan1_kernel(const int* __restrict__ cnt, int* __restrict__ off,
                             int* __restrict__ blksum, int n) {
    __shared__ int tmp[256];
    int t = threadIdx.x, i = blockIdx.x * 256 + t;
    int v = (i < n) ? cnt[i] : 0;
    tmp[t] = v;
    __syncthreads();
    for (int s = 1; s < 256; s <<= 1) {
        int add = (t >= s) ? tmp[t - s] : 0;
        __syncthreads();
        tmp[t] += add;
        __syncthreads();
    }
    if (i < n) off[i] = tmp[t] - v;  // exclusive within block
    if (t == 255) blksum[blockIdx.x] = tmp[255];
}

__global__ void scan2_kernel(int* __restrict__ blksum, int nb) {
    __shared__ int tmp[256];
    int t = threadIdx.x;
    int v = (t < nb) ? blksum[t] : 0;
    tmp[t] = v;
    __syncthreads();
    for (int s = 1; s < 256; s <<= 1) {
        int add = (t >= s) ? tmp[t - s] : 0;
        __syncthreads();
        tmp[t] += add;
        __syncthreads();
    }
    if (t < nb) blksum[t] = tmp[t] - v;  // exclusive, in place
}

__global__ void scan3_kernel(int* __restrict__ off, const int* __restrict__ blksum,
                             int n) {
    int i = blockIdx.x * blockDim.x + threadIdx.x;
    if (i < n) off[i] += blksum[i >> 8];
}

__global__ void fill_kernel(const int* __restrict__ src, const int* __restrict__ dst,
                            const int* __restrict__ off, int* __restrict__ cur,
                            int* __restrict__ srcs, int e_cnt) {
    int e = blockIdx.x * blockDim.x + threadIdx.x;
    if (e >= e_cnt) return;
    int d = dst[e];
    int p = off[d] + atomicAdd(&cur[d], 1);
    srcs[p] = src[e];
}

// ---------- fused softmax-gather: one wave per destination node ----------
__global__ __launch_bounds__(256) void gat_gather_kernel(
    const int* __restrict__ off, const int* __restrict__ cnt,
    const int* __restrict__ srcs,
    const float* __restrict__ es, const float* __restrict__ ed,
    const float* __restrict__ ab, const float* __restrict__ Wh,
    float* __restrict__ out, float coeff, int accum, int n) {
    int wid = (blockIdx.x * blockDim.x + threadIdx.x) >> 6;
    if (wid >= n) return;
    int lane = threadIdx.x & 63;
    int o = lane * 4, hh = o >> 5;
    int start = off[wid], deg = cnt[wid];
    float edv = ed[wid * 8 + hh] + ab[hh];
    // pass 1: exact per-head max over incident edges
    float m = -1e30f;
    for (int j = 0; j < deg; ++j) {
        int s = srcs[start + j];
        float e = es[s * 8 + hh] + edv;
        e = e > 0.f ? e : ALPHA * e;
        m = fmaxf(m, e);
    }
    // pass 2: accumulate exp(e-m) and exp(e-m)*Wh[src] together
    float psum = 0.f;
    float4 acc = make_float4(0.f, 0.f, 0.f, 0.f);
    for (int j = 0; j < deg; ++j) {
        int s = srcs[start + j];
        float e = es[s * 8 + hh] + edv;
        e = e > 0.f ? e : ALPHA * e;
        float p = expf(e - m);
        psum += p;
        float4 v = *(const float4*)(Wh + (size_t)s * FEATS + o);
        acc.x += p * v.x; acc.y += p * v.y;
        acc.z += p * v.z; acc.w += p * v.w;
    }
    float sc = (deg > 0) ? (coeff / psum) : 0.f;
    float* op = out + (size_t)wid * FEATS + o;
    float4 r = make_float4(acc.x * sc, acc.y * sc, acc.z * sc, acc.w * sc);
    if (accum) {
        float4 prev = *(const float4*)op;
        r.x += prev.x; r.y += prev.y; r.z += prev.z; r.w += prev.w;
    }
    *(float4*)op = r;
}

// ---------- GRU elementwise ----------
__global__ void gru_ew_kernel(const float* __restrict__ gi, const float* __restrict__ gh,
                              const float* __restrict__ hmix, float* __restrict__ out,
                              int rows, int row0) {
    int i = blockIdx.x * blockDim.x + threadIdx.x;
    if (i >= rows * FEATS) return;
    int r = i >> 8, j = i & 255;
    const float* gir = gi + (size_t)r * GRUC;
    const float* ghr = gh + (size_t)r * GRUC;
    float ir = gir[j], iz = gir[256 + j], in_ = gir[512 + j];
    float hr = ghr[j], hz = ghr[256 + j], hn = ghr[512 + j];
    float rr = 1.f / (1.f + expf(-(ir + hr)));
    float zz = 1.f / (1.f + expf(-(iz + hz)));
    float nn = tanhf(in_ + rr * hn);
    float hm = hmix[(size_t)(row0 + r) * FEATS + j];
    out[(size_t)(row0 + r) * FEATS + j] = (1.f - zz) * nn + zz * hm;
}

// ---------- launch ----------
extern "C" void kernel_launch(void* const* d_in, const int* in_sizes, int n_in,
                              void* d_out, int out_size, void* d_ws, size_t ws_size,
                              hipStream_t stream) {
    const float* h        = (const float*)d_in[0];
    const float* hp_cnt   = (const float*)d_in[1];
    const float* hp_sup   = (const float*)d_in[2];
    const float* hp_dst   = (const float*)d_in[3];
    const float* W_gat    = (const float*)d_in[4];
    const float* b_gat    = (const float*)d_in[5];
    const float* as_gat   = (const float*)d_in[6];
    const float* ad_gat   = (const float*)d_in[7];
    const float* ab_gat   = (const float*)d_in[8];
    const float* W_x      = (const float*)d_in[9];
    const float* b_x      = (const float*)d_in[10];
    const float* as_x     = (const float*)d_in[11];
    const float* ad_x     = (const float*)d_in[12];
    const float* ab_x     = (const float*)d_in[13];
    const float* W_ih     = (const float*)d_in[14];
    const float* W_hh     = (const float*)d_in[15];
    const float* b_ih     = (const float*)d_in[16];
    const float* b_hh     = (const float*)d_in[17];
    const int* e_src      = (const int*)d_in[18];
    const int* e_dst      = (const int*)d_in[19];
    const int* ec_src     = (const int*)d_in[20];
    const int* ec_dst     = (const int*)d_in[21];
    const int* es_src     = (const int*)d_in[22];
    const int* es_dst     = (const int*)d_in[23];

    const int N = in_sizes[0] / FEATS;
    const int E = in_sizes[18];
    const int N8 = N * HEADS;
    const int NBLK = (N + 255) / 256;  // scan blocks (<=256 required)

    const size_t NB = (size_t)N * FEATS * sizeof(float);
    const size_t N8B = (size_t)N8 * sizeof(float);
    char* ws = (char*)d_ws;
    size_t p = 0;
    float* bufA = (float*)(ws + p); p += NB;       // Wh src side / gi chunk
    float* bufB = (float*)(ws + p); p += NB;       // Wh dst side / gh chunk
    float* hmix = (float*)(ws + p); p += NB;
    float* esb  = (float*)(ws + p); p += N8B;
    float* edb  = (float*)(ws + p); p += N8B;
    int*   cntb = (int*)(ws + p); p += (size_t)N * 4;
    int*   offb = (int*)(ws + p); p += (size_t)N * 4;
    int*   curb = (int*)(ws + p); p += (size_t)N * 4;
    int*   blks = (int*)(ws + p); p += 256 * 4;
    int*   srcs = (int*)(ws + p); p += (size_t)E * 4;
    float* xbuf = (float*)d_out;  // x lives in d_out; overwritten by GRU

    const dim3 blk(256);
    const dim3 gProj((N + 63) / 64, FEATS / 64);
    const int gN8 = (N8 + 255) / 256;
    const int gE = (E + 255) / 256;
    const int gGather = (N * 64 + 255) / 256;

    auto build_csr = [&](const int* src, const int* dst) {
        hipMemsetAsync(cntb, 0, (size_t)N * 4, stream);
        hipMemsetAsync(curb, 0, (size_t)N * 4, stream);
        count_kernel<<<gE, blk, 0, stream>>>(dst, cntb, E);
        scan1_kernel<<<NBLK, blk, 0, stream>>>(cntb, offb, blks, N);
        scan2_kernel<<<1, blk, 0, stream>>>(blks, NBLK);
        scan3_kernel<<<(N + 255) / 256, blk, 0, stream>>>(offb, blks, N);
        fill_kernel<<<gE, blk, 0, stream>>>(src, dst, offb, curb, srcs, E);
    };

    // ---- GAT1: intra-turn on h ----
    gemm_f32<0><<<gProj, blk, 0, stream>>>(h, W_gat, b_gat, bufA, N, FEATS, FEATS);
    esed_kernel<1, 1><<<gN8, blk, 0, stream>>>(bufA, as_gat, ad_gat, esb, edb, N);
    build_csr(e_src, e_dst);
    gat_gather_kernel<<<gGather, blk, 0, stream>>>(offb, cntb, srcs, esb, edb,
                                                   ab_gat, bufA, xbuf, 1.0f, 0, N);

    // ---- GAT2: counter (hp_counter -> hp_dst) ----
    gemm_f32<0><<<gProj, blk, 0, stream>>>(hp_cnt, W_x, b_x, bufA, N, FEATS, FEATS);
    gemm_f32<0><<<gProj, blk, 0, stream>>>(hp_dst, W_x, b_x, bufB, N, FEATS, FEATS);
    esed_kernel<1, 0><<<gN8, blk, 0, stream>>>(bufA, as_x, nullptr, esb, nullptr, N);
    esed_kernel<0, 1><<<gN8, blk, 0, stream>>>(bufB, nullptr, ad_x, nullptr, edb, N);
    build_csr(ec_src, ec_dst);
    gat_gather_kernel<<<gGather, blk, 0, stream>>>(offb, cntb, srcs, esb, edb,
                                                   ab_x, bufA, hmix, 0.5f, 0, N);

    // ---- GAT3: support (hp_support -> hp_dst); ed (from hp_dst) unchanged ----
    gemm_f32<0><<<gProj, blk, 0, stream>>>(hp_sup, W_x, b_x, bufA, N, FEATS, FEATS);
    esed_kernel<1, 0><<<gN8, blk, 0, stream>>>(bufA, as_x, nullptr, esb, nullptr, N);
    build_csr(es_src, es_dst);
    gat_gather_kernel<<<gGather, blk, 0, stream>>>(offb, cntb, srcs, esb, edb,
                                                   ab_x, bufA, hmix, 0.5f, 1, N);

    // ---- GRU, chunked so gi/gh fit in bufA/bufB ----
    const int CH = 16384;
    for (int row0 = 0; row0 < N; row0 += CH) {
        int rows = min(CH, N - row0);
        dim3 gG((rows + 63) / 64, GRUC / 64);
        gemm_f32<1><<<gG, blk, 0, stream>>>(xbuf + (size_t)row0 * FEATS, W_ih, b_ih,
                                            bufA, rows, GRUC, FEATS);
        gemm_f32<1><<<gG, blk, 0, stream>>>(hmix + (size_t)row0 * FEATS, W_hh, b_hh,
                                            bufB, rows, GRUC, FEATS);
        int gEw = (rows * FEATS + 255) / 256;
        gru_ew_kernel<<<gEw, blk, 0, stream>>>(bufA, bufB, hmix, (float*)d_out, rows, row0);
    }
}

// Round 3
// 812.717 us; speedup vs baseline: 7.7343x; 1.9857x over previous
//
#include <hip/hip_runtime.h>
#include <math.h>

#define ALPHA 0.2f

constexpr int FEATS = 256;   // NFEATS == NHIDS == K for every GEMM
constexpr int HEADS = 8;

typedef unsigned short u16;
typedef __attribute__((ext_vector_type(8))) short bf16x8;
typedef __attribute__((ext_vector_type(4))) float f32x4;

// ---------- bf16 helpers ----------
__device__ __forceinline__ u16 f2b(float f) {            // RNE
    unsigned u = __float_as_uint(f);
    u += 0x7FFF + ((u >> 16) & 1);
    return (u16)(u >> 16);
}
__device__ __forceinline__ float b2f(u16 x) {
    return __uint_as_float(((unsigned)x) << 16);
}
// pack two f32 into one u32 of 2 bf16 (truncate) via v_perm
__device__ __forceinline__ unsigned pk2(float lo, float hi) {
    return __builtin_amdgcn_perm(__float_as_uint(hi), __float_as_uint(lo), 0x07060302u);
}

__device__ __forceinline__ void gload16(const void* g, void* l) {
    __builtin_amdgcn_global_load_lds(
        (const __attribute__((address_space(1))) unsigned int*)g,
        (__attribute__((address_space(3))) unsigned int*)l, 16, 0, 0);
}

// ---------- bf16 MFMA GEMM: C_bf16[M][Ncols] = A[M][256] * B[Ncols][256]^T + bias ----------
// AF32=1: A is fp32 (staged raw, converted at fragment load). AF32=0: A is bf16.
// B is bf16 [Ncols][K=256] (N-major). BM=BN=128, BK=64, 4 waves (2x2), 16x16x32 MFMA.
template <int AF32>
__global__ __launch_bounds__(256) void gemm_mfma(
    const void* __restrict__ Ap, const u16* __restrict__ B,
    const float* __restrict__ bias, u16* __restrict__ C,
    int M, int Ncols) {
    __shared__ char As_raw[AF32 ? 32768 : 16384];  // 128 x 64, swizzled
    __shared__ char Bs_raw[16384];                 // 128 x 64, swizzled
    const int tid = threadIdx.x;
    const int lane = tid & 63;
    const int wid = tid >> 6;
    const int wr = wid >> 1, wc = wid & 1;
    const int bm = blockIdx.x * 128;
    const int bn = blockIdx.y * 128;

    f32x4 acc[4][4];
#pragma unroll
    for (int m = 0; m < 4; ++m)
#pragma unroll
        for (int n = 0; n < 4; ++n) acc[m][n] = (f32x4)0.f;

    for (int kb = 0; kb < 4; ++kb) {
        const int k0g = kb * 64;
        // ---- stage A tile ----
        if (AF32) {
            const float* A = (const float*)Ap;
#pragma unroll
            for (int i = 0; i < 8; ++i) {
                int s = i * 256 + tid;          // 16B slot, 2048 total
                int row = s >> 4, c16 = s & 15;
                int c32 = c16 >> 1, half = c16 & 1;
                int gr = min(bm + row, M - 1);
                int gcol = k0g + ((c32 ^ (row & 7)) * 8 + half * 4);
                gload16(A + (size_t)gr * 256 + gcol, As_raw + s * 16);
            }
        } else {
            const u16* A = (const u16*)Ap;
#pragma unroll
            for (int i = 0; i < 4; ++i) {
                int s = i * 256 + tid;          // 16B slot, 1024 total
                int row = s >> 3, c16 = s & 7;
                int gr = min(bm + row, M - 1);
                int gcol = k0g + (c16 ^ (row & 7)) * 8;
                gload16(A + (size_t)gr * 256 + gcol, As_raw + s * 16);
            }
        }
        // ---- stage B tile ----
#pragma unroll
        for (int i = 0; i < 4; ++i) {
            int s = i * 256 + tid;
            int row = s >> 3, c16 = s & 7;
            int gcol = k0g + (c16 ^ (row & 7)) * 8;
            gload16(B + (size_t)(bn + row) * 256 + gcol, Bs_raw + s * 16);
        }
        __syncthreads();
        // ---- compute: 2 k-steps of K=32 ----
#pragma unroll
        for (int kk = 0; kk < 2; ++kk) {
            const int ko = kk * 32 + (lane >> 4) * 8;   // k within tile
            const int kc = ko >> 3;                      // 16B-chunk index (bf16)
            bf16x8 af[4], bfr[4];
#pragma unroll
            for (int m = 0; m < 4; ++m) {
                int row = wr * 64 + m * 16 + (lane & 15);
                if (AF32) {
                    int byte = row * 256 + ((kc ^ (row & 7)) << 5);
                    f32x4 lo = *(const f32x4*)(As_raw + byte);
                    f32x4 hi = *(const f32x4*)(As_raw + byte + 16);
                    union { unsigned u[4]; bf16x8 v; } cv;
                    cv.u[0] = pk2(lo.x, lo.y); cv.u[1] = pk2(lo.z, lo.w);
                    cv.u[2] = pk2(hi.x, hi.y); cv.u[3] = pk2(hi.z, hi.w);
                    af[m] = cv.v;
                } else {
                    int byte = row * 128 + ((kc ^ (row & 7)) << 4);
                    af[m] = *(const bf16x8*)(As_raw + byte);
                }
            }
#pragma unroll
            for (int n = 0; n < 4; ++n) {
                int row = wc * 64 + n * 16 + (lane & 15);
                int byte = row * 128 + ((kc ^ (row & 7)) << 4);
                bfr[n] = *(const bf16x8*)(Bs_raw + byte);
            }
#pragma unroll
            for (int m = 0; m < 4; ++m)
#pragma unroll
                for (int n = 0; n < 4; ++n)
                    acc[m][n] = __builtin_amdgcn_mfma_f32_16x16x32_bf16(
                        af[m], bfr[n], acc[m][n], 0, 0, 0);
        }
        __syncthreads();
    }
    // ---- epilogue: C/D layout col=lane&15, row=(lane>>4)*4+j ----
#pragma unroll
    for (int m = 0; m < 4; ++m) {
#pragma unroll
        for (int j = 0; j < 4; ++j) {
            int gr = bm + wr * 64 + m * 16 + (lane >> 4) * 4 + j;
            if (gr < M) {
#pragma unroll
                for (int n = 0; n < 4; ++n) {
                    int gc = bn + wc * 64 + n * 16 + (lane & 15);
                    C[(size_t)gr * Ncols + gc] = f2b(acc[m][n][j] + bias[gc]);
                }
            }
        }
    }
}

// ---------- weight prep ----------
// W [8][256][32] f32 -> Bt [256][256] bf16, Bt[h*32+d][f] = W[h][f][d]
__global__ void wt_head_kernel(const float* __restrict__ W, u16* __restrict__ Bt) {
    int i = blockIdx.x * 256 + threadIdx.x;  // 65536
    int n = i >> 8, f = i & 255;
    int h2 = n >> 5, d = n & 31;
    Bt[i] = f2b(W[(h2 * 256 + f) * 32 + d]);
}
__global__ void wt_cvt_kernel(const float* __restrict__ W, u16* __restrict__ Bt, int n) {
    int i = blockIdx.x * 256 + threadIdx.x;
    if (i < n) Bt[i] = f2b(W[i]);
}

// ---------- es/ed per (node, head), bf16 Wh ----------
template <int DO_S, int DO_D>
__global__ void esed_kernel(const u16* __restrict__ Wh,
                            const float* __restrict__ a_s,
                            const float* __restrict__ a_d,
                            float* __restrict__ es, float* __restrict__ ed,
                            int n) {
    int idx = blockIdx.x * blockDim.x + threadIdx.x;
    if (idx >= n * 8) return;
    int node = idx >> 3, h = idx & 7;
    const u16* row = Wh + (size_t)node * FEATS + h * 32;
    float ss = 0.f, dd = 0.f;
#pragma unroll
    for (int i = 0; i < 8; ++i) {
        ushort4 v = *(const ushort4*)(row + i * 4);
        float f0 = b2f(v.x), f1 = b2f(v.y), f2 = b2f(v.z), f3 = b2f(v.w);
        if (DO_S) {
            const float4 w = *(const float4*)(a_s + h * 32 + i * 4);
            ss += f0 * w.x + f1 * w.y + f2 * w.z + f3 * w.w;
        }
        if (DO_D) {
            const float4 w = *(const float4*)(a_d + h * 32 + i * 4);
            dd += f0 * w.x + f1 * w.y + f2 * w.z + f3 * w.w;
        }
    }
    if (DO_S) es[idx] = ss;
    if (DO_D) ed[idx] = dd;
}

// ---------- CSR build ----------
__global__ void count_kernel(const int* __restrict__ dst, int* __restrict__ cnt,
                             int e_cnt) {
    int e = blockIdx.x * blockDim.x + threadIdx.x;
    if (e < e_cnt) atomicAdd(&cnt[dst[e]], 1);
}
__global__ void scan1_kernel(const int* __restrict__ cnt, int* __restrict__ off,
                             int* __restrict__ blksum, int n) {
    __shared__ int tmp[256];
    int t = threadIdx.x, i = blockIdx.x * 256 + t;
    int v = (i < n) ? cnt[i] : 0;
    tmp[t] = v;
    __syncthreads();
    for (int s = 1; s < 256; s <<= 1) {
        int add = (t >= s) ? tmp[t - s] : 0;
        __syncthreads();
        tmp[t] += add;
        __syncthreads();
    }
    if (i < n) off[i] = tmp[t] - v;
    if (t == 255) blksum[blockIdx.x] = tmp[255];
}
__global__ void scan2_kernel(int* __restrict__ blksum, int nb) {
    __shared__ int tmp[256];
    int t = threadIdx.x;
    int v = (t < nb) ? blksum[t] : 0;
    tmp[t] = v;
    __syncthreads();
    for (int s = 1; s < 256; s <<= 1) {
        int add = (t >= s) ? tmp[t - s] : 0;
        __syncthreads();
        tmp[t] += add;
        __syncthreads();
    }
    if (t < nb) blksum[t] = tmp[t] - v;
}
__global__ void scan3_kernel(int* __restrict__ off, const int* __restrict__ blksum,
                             int n) {
    int i = blockIdx.x * blockDim.x + threadIdx.x;
    if (i < n) off[i] += blksum[i >> 8];
}
__global__ void fill_kernel(const int* __restrict__ src, const int* __restrict__ dst,
                            const int* __restrict__ off, int* __restrict__ cur,
                            int* __restrict__ srcs, int e_cnt) {
    int e = blockIdx.x * blockDim.x + threadIdx.x;
    if (e >= e_cnt) return;
    int d = dst[e];
    int p = off[d] + atomicAdd(&cur[d], 1);
    srcs[p] = src[e];
}

// ---------- fused softmax-gather: one wave per destination node (bf16 Wh/out) ----------
__global__ __launch_bounds__(256) void gat_gather_kernel(
    const int* __restrict__ off, const int* __restrict__ cnt,
    const int* __restrict__ srcs,
    const float* __restrict__ es, const float* __restrict__ ed,
    const float* __restrict__ ab, const u16* __restrict__ Wh,
    u16* __restrict__ out, float coeff, int accum, int n) {
    int wid = (blockIdx.x * blockDim.x + threadIdx.x) >> 6;
    if (wid >= n) return;
    int lane = threadIdx.x & 63;
    int o = lane * 4, hh = o >> 5;
    int start = off[wid], deg = cnt[wid];
    float edv = ed[wid * 8 + hh] + ab[hh];
    float m = -1e30f;
    for (int j = 0; j < deg; ++j) {
        float e = es[srcs[start + j] * 8 + hh] + edv;
        e = e > 0.f ? e : ALPHA * e;
        m = fmaxf(m, e);
    }
    float psum = 0.f;
    float ax = 0.f, ay = 0.f, az = 0.f, aw = 0.f;
    for (int j = 0; j < deg; ++j) {
        int s = srcs[start + j];
        float e = es[s * 8 + hh] + edv;
        e = e > 0.f ? e : ALPHA * e;
        float p = expf(e - m);
        psum += p;
        ushort4 v = *(const ushort4*)(Wh + (size_t)s * FEATS + o);
        ax += p * b2f(v.x); ay += p * b2f(v.y);
        az += p * b2f(v.z); aw += p * b2f(v.w);
    }
    float sc = (deg > 0) ? (coeff / psum) : 0.f;
    float rx = ax * sc, ry = ay * sc, rz = az * sc, rw = aw * sc;
    u16* op = out + (size_t)wid * FEATS + o;
    if (accum) {
        ushort4 prev = *(const ushort4*)op;
        rx += b2f(prev.x); ry += b2f(prev.y);
        rz += b2f(prev.z); rw += b2f(prev.w);
    }
    ushort4 r;
    r.x = f2b(rx); r.y = f2b(ry); r.z = f2b(rz); r.w = f2b(rw);
    *(ushort4*)op = r;
}

// ---------- GRU elementwise (bf16 gi/gh/hmix -> f32 out), 2 cols/thread ----------
__global__ void gru_ew_kernel(const u16* __restrict__ gi, const u16* __restrict__ gh,
                              const u16* __restrict__ hmix, float* __restrict__ out,
                              int rows, int row0) {
    int i = blockIdx.x * blockDim.x + threadIdx.x;
    if (i >= rows * 128) return;
    int r = i >> 7, j = (i & 127) * 2;
    const u16* gir = gi + (size_t)r * 768;
    const u16* ghr = gh + (size_t)r * 768;
    ushort2 ir = *(const ushort2*)(gir + j);
    ushort2 iz = *(const ushort2*)(gir + 256 + j);
    ushort2 in_ = *(const ushort2*)(gir + 512 + j);
    ushort2 hr = *(const ushort2*)(ghr + j);
    ushort2 hz = *(const ushort2*)(ghr + 256 + j);
    ushort2 hn = *(const ushort2*)(ghr + 512 + j);
    ushort2 hm = *(const ushort2*)(hmix + (size_t)(row0 + r) * FEATS + j);
    float2 res;
    {
        float rr = 1.f / (1.f + expf(-(b2f(ir.x) + b2f(hr.x))));
        float zz = 1.f / (1.f + expf(-(b2f(iz.x) + b2f(hz.x))));
        float nn = tanhf(b2f(in_.x) + rr * b2f(hn.x));
        res.x = (1.f - zz) * nn + zz * b2f(hm.x);
    }
    {
        float rr = 1.f / (1.f + expf(-(b2f(ir.y) + b2f(hr.y))));
        float zz = 1.f / (1.f + expf(-(b2f(iz.y) + b2f(hz.y))));
        float nn = tanhf(b2f(in_.y) + rr * b2f(hn.y));
        res.y = (1.f - zz) * nn + zz * b2f(hm.y);
    }
    *(float2*)(out + (size_t)(row0 + r) * FEATS + j) = res;
}

// ---------- launch ----------
extern "C" void kernel_launch(void* const* d_in, const int* in_sizes, int n_in,
                              void* d_out, int out_size, void* d_ws, size_t ws_size,
                              hipStream_t stream) {
    const float* h        = (const float*)d_in[0];
    const float* hp_cnt   = (const float*)d_in[1];
    const float* hp_sup   = (const float*)d_in[2];
    const float* hp_dst   = (const float*)d_in[3];
    const float* W_gat    = (const float*)d_in[4];
    const float* b_gat    = (const float*)d_in[5];
    const float* as_gat   = (const float*)d_in[6];
    const float* ad_gat   = (const float*)d_in[7];
    const float* ab_gat   = (const float*)d_in[8];
    const float* W_x      = (const float*)d_in[9];
    const float* b_x      = (const float*)d_in[10];
    const float* as_x     = (const float*)d_in[11];
    const float* ad_x     = (const float*)d_in[12];
    const float* ab_x     = (const float*)d_in[13];
    const float* W_ih     = (const float*)d_in[14];
    const float* W_hh     = (const float*)d_in[15];
    const float* b_ih     = (const float*)d_in[16];
    const float* b_hh     = (const float*)d_in[17];
    const int* e_src      = (const int*)d_in[18];
    const int* e_dst      = (const int*)d_in[19];
    const int* ec_src     = (const int*)d_in[20];
    const int* ec_dst     = (const int*)d_in[21];
    const int* es_src     = (const int*)d_in[22];
    const int* es_dst     = (const int*)d_in[23];

    const int N = in_sizes[0] / FEATS;
    const int E = in_sizes[18];
    const int N8 = N * HEADS;
    const int NBLK = (N + 255) / 256;

    char* ws = (char*)d_ws;
    size_t p = 0;
    u16* WhS   = (u16*)(ws + p); p += (size_t)N * FEATS * 2;
    u16* WhD   = (u16*)(ws + p); p += (size_t)N * FEATS * 2;
    u16* xb    = (u16*)(ws + p); p += (size_t)N * FEATS * 2;
    u16* hmixb = (u16*)(ws + p); p += (size_t)N * FEATS * 2;
    float* esb = (float*)(ws + p); p += (size_t)N8 * 4;
    float* edb = (float*)(ws + p); p += (size_t)N8 * 4;
    int* cntb  = (int*)(ws + p); p += (size_t)N * 4;
    int* offb  = (int*)(ws + p); p += (size_t)N * 4;
    int* curb  = (int*)(ws + p); p += (size_t)N * 4;
    int* blks  = (int*)(ws + p); p += 1024;
    int* srcs  = (int*)(ws + p); p += (size_t)E * 4;
    u16* Bgat  = (u16*)(ws + p); p += 65536 * 2;
    u16* Bx    = (u16*)(ws + p); p += 65536 * 2;
    u16* Bih   = (u16*)(ws + p); p += 196608 * 2;
    u16* Bhh   = (u16*)(ws + p); p += 196608 * 2;
    const int CH = 16384;
    u16* giB   = (u16*)(ws + p); p += (size_t)CH * 768 * 2;
    u16* ghB   = (u16*)(ws + p); p += (size_t)CH * 768 * 2;

    const dim3 blk(256);
    const dim3 gProj((N + 127) / 128, FEATS / 128);
    const int gN8 = (N8 + 255) / 256;
    const int gE = (E + 255) / 256;
    const int gGather = (N * 64 + 255) / 256;

    auto build_csr = [&](const int* src, const int* dst) {
        hipMemsetAsync(cntb, 0, (size_t)N * 4, stream);
        hipMemsetAsync(curb, 0, (size_t)N * 4, stream);
        count_kernel<<<gE, blk, 0, stream>>>(dst, cntb, E);
        scan1_kernel<<<NBLK, blk, 0, stream>>>(cntb, offb, blks, N);
        scan2_kernel<<<1, blk, 0, stream>>>(blks, NBLK);
        scan3_kernel<<<(N + 255) / 256, blk, 0, stream>>>(offb, blks, N);
        fill_kernel<<<gE, blk, 0, stream>>>(src, dst, offb, curb, srcs, E);
    };

    // ---- weight prep (bf16, [N][K] layout) ----
    wt_head_kernel<<<256, blk, 0, stream>>>(W_gat, Bgat);
    wt_head_kernel<<<256, blk, 0, stream>>>(W_x, Bx);
    wt_cvt_kernel<<<768, blk, 0, stream>>>(W_ih, Bih, 196608);
    wt_cvt_kernel<<<768, blk, 0, stream>>>(W_hh, Bhh, 196608);

    // ---- GAT1: intra-turn on h ----
    gemm_mfma<1><<<gProj, blk, 0, stream>>>(h, Bgat, b_gat, WhS, N, FEATS);
    esed_kernel<1, 1><<<gN8, blk, 0, stream>>>(WhS, as_gat, ad_gat, esb, edb, N);
    build_csr(e_src, e_dst);
    gat_gather_kernel<<<gGather, blk, 0, stream>>>(offb, cntb, srcs, esb, edb,
                                                   ab_gat, WhS, xb, 1.0f, 0, N);

    // ---- GAT2: counter (hp_counter -> hp_dst) ----
    gemm_mfma<1><<<gProj, blk, 0, stream>>>(hp_cnt, Bx, b_x, WhS, N, FEATS);
    gemm_mfma<1><<<gProj, blk, 0, stream>>>(hp_dst, Bx, b_x, WhD, N, FEATS);
    esed_kernel<1, 0><<<gN8, blk, 0, stream>>>(WhS, as_x, nullptr, esb, nullptr, N);
    esed_kernel<0, 1><<<gN8, blk, 0, stream>>>(WhD, nullptr, ad_x, nullptr, edb, N);
    build_csr(ec_src, ec_dst);
    gat_gather_kernel<<<gGather, blk, 0, stream>>>(offb, cntb, srcs, esb, edb,
                                                   ab_x, WhS, hmixb, 0.5f, 0, N);

    // ---- GAT3: support (hp_support -> hp_dst); ed (from hp_dst) unchanged ----
    gemm_mfma<1><<<gProj, blk, 0, stream>>>(hp_sup, Bx, b_x, WhS, N, FEATS);
    esed_kernel<1, 0><<<gN8, blk, 0, stream>>>(WhS, as_x, nullptr, esb, nullptr, N);
    build_csr(es_src, es_dst);
    gat_gather_kernel<<<gGather, blk, 0, stream>>>(offb, cntb, srcs, esb, edb,
                                                   ab_x, WhS, hmixb, 0.5f, 1, N);

    // ---- GRU, chunked ----
    for (int row0 = 0; row0 < N; row0 += CH) {
        int rows = min(CH, N - row0);
        dim3 gG((rows + 127) / 128, 768 / 128);
        gemm_mfma<0><<<gG, blk, 0, stream>>>(xb + (size_t)row0 * FEATS, Bih, b_ih,
                                             giB, rows, 768);
        gemm_mfma<0><<<gG, blk, 0, stream>>>(hmixb + (size_t)row0 * FEATS, Bhh, b_hh,
                                             ghB, rows, 768);
        int gEw = (rows * 128 + 255) / 256;
        gru_ew_kernel<<<gEw, blk, 0, stream>>>(giB, ghB, hmixb, (float*)d_out, rows, row0);
    }
}

// Round 5
// 648.293 us; speedup vs baseline: 9.6959x; 1.2536x over previous
//
#include <hip/hip_runtime.h>
#include <math.h>

#define ALPHA 0.2f
#define LOG2E 1.44269504088896f

constexpr int FEATS = 256;   // NFEATS == NHIDS == K for every GEMM
constexpr int HEADS = 8;

typedef unsigned short u16;
typedef __attribute__((ext_vector_type(8))) short bf16x8;
typedef __attribute__((ext_vector_type(4))) float f32x4;

// ---------- bf16 helpers ----------
__device__ __forceinline__ u16 f2b(float f) {            // RNE
    unsigned u = __float_as_uint(f);
    u += 0x7FFF + ((u >> 16) & 1);
    return (u16)(u >> 16);
}
__device__ __forceinline__ float b2f(u16 x) {
    return __uint_as_float(((unsigned)x) << 16);
}
// pack two f32 into one u32 of 2 bf16 (truncate) via v_perm
__device__ __forceinline__ unsigned pk2(float lo, float hi) {
    return __builtin_amdgcn_perm(__float_as_uint(hi), __float_as_uint(lo), 0x07060302u);
}

__device__ __forceinline__ void gload16(const void* g, void* l) {
    __builtin_amdgcn_global_load_lds(
        (const __attribute__((address_space(1))) unsigned int*)g,
        (__attribute__((address_space(3))) unsigned int*)l, 16, 0, 0);
}

// ---------- bf16 MFMA GEMM: C_bf16[M][Ncols] = A[M][256] * B[Ncols][256]^T + bias ----------
// AF32=1: A is fp32 (staged raw, converted at fragment load). AF32=0: A is bf16.
template <int AF32>
__global__ __launch_bounds__(256) void gemm_mfma(
    const void* __restrict__ Ap, const u16* __restrict__ B,
    const float* __restrict__ bias, u16* __restrict__ C,
    int M, int Ncols) {
    __shared__ char As_raw[AF32 ? 32768 : 16384];  // 128 x 64, swizzled
    __shared__ char Bs_raw[16384];                 // 128 x 64, swizzled
    const int tid = threadIdx.x;
    const int lane = tid & 63;
    const int wid = tid >> 6;
    const int wr = wid >> 1, wc = wid & 1;
    const int bm = blockIdx.x * 128;
    const int bn = blockIdx.y * 128;

    f32x4 acc[4][4];
#pragma unroll
    for (int m = 0; m < 4; ++m)
#pragma unroll
        for (int n = 0; n < 4; ++n) acc[m][n] = (f32x4)0.f;

    for (int kb = 0; kb < 4; ++kb) {
        const int k0g = kb * 64;
        if (AF32) {
            const float* A = (const float*)Ap;
#pragma unroll
            for (int i = 0; i < 8; ++i) {
                int s = i * 256 + tid;          // 16B slot, 2048 total
                int row = s >> 4, c16 = s & 15;
                int c32 = c16 >> 1, half = c16 & 1;
                int gr = min(bm + row, M - 1);
                int gcol = k0g + ((c32 ^ (row & 7)) * 8 + half * 4);
                gload16(A + (size_t)gr * 256 + gcol, As_raw + s * 16);
            }
        } else {
            const u16* A = (const u16*)Ap;
#pragma unroll
            for (int i = 0; i < 4; ++i) {
                int s = i * 256 + tid;          // 16B slot, 1024 total
                int row = s >> 3, c16 = s & 7;
                int gr = min(bm + row, M - 1);
                int gcol = k0g + (c16 ^ (row & 7)) * 8;
                gload16(A + (size_t)gr * 256 + gcol, As_raw + s * 16);
            }
        }
#pragma unroll
        for (int i = 0; i < 4; ++i) {
            int s = i * 256 + tid;
            int row = s >> 3, c16 = s & 7;
            int gcol = k0g + (c16 ^ (row & 7)) * 8;
            gload16(B + (size_t)(bn + row) * 256 + gcol, Bs_raw + s * 16);
        }
        __syncthreads();
#pragma unroll
        for (int kk = 0; kk < 2; ++kk) {
            const int ko = kk * 32 + (lane >> 4) * 8;
            const int kc = ko >> 3;
            bf16x8 af[4], bfr[4];
#pragma unroll
            for (int m = 0; m < 4; ++m) {
                int row = wr * 64 + m * 16 + (lane & 15);
                if (AF32) {
                    int byte = row * 256 + ((kc ^ (row & 7)) << 5);
                    f32x4 lo = *(const f32x4*)(As_raw + byte);
                    f32x4 hi = *(const f32x4*)(As_raw + byte + 16);
                    union { unsigned u[4]; bf16x8 v; } cv;
                    cv.u[0] = pk2(lo.x, lo.y); cv.u[1] = pk2(lo.z, lo.w);
                    cv.u[2] = pk2(hi.x, hi.y); cv.u[3] = pk2(hi.z, hi.w);
                    af[m] = cv.v;
                } else {
                    int byte = row * 128 + ((kc ^ (row & 7)) << 4);
                    af[m] = *(const bf16x8*)(As_raw + byte);
                }
            }
#pragma unroll
            for (int n = 0; n < 4; ++n) {
                int row = wc * 64 + n * 16 + (lane & 15);
                int byte = row * 128 + ((kc ^ (row & 7)) << 4);
                bfr[n] = *(const bf16x8*)(Bs_raw + byte);
            }
#pragma unroll
            for (int m = 0; m < 4; ++m)
#pragma unroll
                for (int n = 0; n < 4; ++n)
                    acc[m][n] = __builtin_amdgcn_mfma_f32_16x16x32_bf16(
                        af[m], bfr[n], acc[m][n], 0, 0, 0);
        }
        __syncthreads();
    }
#pragma unroll
    for (int m = 0; m < 4; ++m) {
#pragma unroll
        for (int j = 0; j < 4; ++j) {
            int gr = bm + wr * 64 + m * 16 + (lane >> 4) * 4 + j;
            if (gr < M) {
#pragma unroll
                for (int n = 0; n < 4; ++n) {
                    int gc = bn + wc * 64 + n * 16 + (lane & 15);
                    C[(size_t)gr * Ncols + gc] = f2b(acc[m][n][j] + bias[gc]);
                }
            }
        }
    }
}

// ---------- merged weight prep ----------
// [0,65536) Bgat from W_gat (head layout), [65536,131072) Bx from W_x,
// [131072,327680) Bih from W_ih, [327680,524288) Bhh from W_hh.
__global__ void prep_kernel(const float* __restrict__ W_gat, const float* __restrict__ W_x,
                            const float* __restrict__ W_ih, const float* __restrict__ W_hh,
                            u16* __restrict__ Bgat, u16* __restrict__ Bx,
                            u16* __restrict__ Bih, u16* __restrict__ Bhh) {
    int i = blockIdx.x * 256 + threadIdx.x;
    if (i < 131072) {
        int j = i & 65535;                     // 65536 is a power of two: ok
        int n = j >> 8, f = j & 255;
        int h2 = n >> 5, d = n & 31;
        const float* W = (i < 65536) ? W_gat : W_x;
        u16* Bt = (i < 65536) ? Bgat : Bx;
        Bt[j] = f2b(W[(h2 * 256 + f) * 32 + d]);
    } else {
        int x = i - 131072;                    // explicit range split (196608 is NOT pow2)
        if (x < 196608) Bih[x] = f2b(W_ih[x]);
        else            Bhh[x - 196608] = f2b(W_hh[x - 196608]);
    }
}

// ---------- es/ed per (node, head), bf16 Wh ----------
template <int DO_S, int DO_D>
__global__ void esed_kernel(const u16* __restrict__ WhS, const u16* __restrict__ WhD,
                            const float* __restrict__ a_s,
                            const float* __restrict__ a_d,
                            float* __restrict__ es, float* __restrict__ ed,
                            int n) {
    int idx = blockIdx.x * blockDim.x + threadIdx.x;
    if (idx >= n * 8) return;
    int node = idx >> 3, h = idx & 7;
    float ss = 0.f, dd = 0.f;
    if (DO_S) {
        const u16* row = WhS + (size_t)node * FEATS + h * 32;
#pragma unroll
        for (int i = 0; i < 8; ++i) {
            ushort4 v = *(const ushort4*)(row + i * 4);
            const float4 w = *(const float4*)(a_s + h * 32 + i * 4);
            ss += b2f(v.x) * w.x + b2f(v.y) * w.y + b2f(v.z) * w.z + b2f(v.w) * w.w;
        }
        es[idx] = ss;
    }
    if (DO_D) {
        const u16* row = WhD + (size_t)node * FEATS + h * 32;
#pragma unroll
        for (int i = 0; i < 8; ++i) {
            ushort4 v = *(const ushort4*)(row + i * 4);
            const float4 w = *(const float4*)(a_d + h * 32 + i * 4);
            dd += b2f(v.x) * w.x + b2f(v.y) * w.y + b2f(v.z) * w.z + b2f(v.w) * w.w;
        }
        ed[idx] = dd;
    }
}

// ---------- batched CSR build over 3 edge lists ----------
__global__ void count3_kernel(const int* __restrict__ d0, const int* __restrict__ d1,
                              const int* __restrict__ d2, int* __restrict__ cnt,
                              int E, int N) {
    int i = blockIdx.x * blockDim.x + threadIdx.x;
    if (i >= 3 * E) return;
    if (i < E) atomicAdd(&cnt[d0[i]], 1);
    else if (i < 2 * E) atomicAdd(&cnt[N + d1[i - E]], 1);
    else atomicAdd(&cnt[2 * N + d2[i - 2 * E]], 1);
}

// 1024 elements per block (256 threads x 4)
__global__ void scan1_kernel(const int* __restrict__ cnt, int* __restrict__ off,
                             int* __restrict__ blksum, int n) {
    __shared__ int tmp[256];
    int t = threadIdx.x;
    int base = blockIdx.x * 1024 + t * 4;
    int v[4];
#pragma unroll
    for (int k = 0; k < 4; ++k) v[k] = (base + k < n) ? cnt[base + k] : 0;
    int s = v[0] + v[1] + v[2] + v[3];
    tmp[t] = s;
    __syncthreads();
    for (int st = 1; st < 256; st <<= 1) {
        int add = (t >= st) ? tmp[t - st] : 0;
        __syncthreads();
        tmp[t] += add;
        __syncthreads();
    }
    int ex = tmp[t] - s;
#pragma unroll
    for (int k = 0; k < 4; ++k) {
        if (base + k < n) off[base + k] = ex;
        ex += v[k];
    }
    if (t == 255) blksum[blockIdx.x] = tmp[255];
}
__global__ void scan2_kernel(int* __restrict__ blksum, int nb) {
    __shared__ int tmp[256];
    int t = threadIdx.x;
    int v = (t < nb) ? blksum[t] : 0;
    tmp[t] = v;
    __syncthreads();
    for (int s = 1; s < 256; s <<= 1) {
        int add = (t >= s) ? tmp[t - s] : 0;
        __syncthreads();
        tmp[t] += add;
        __syncthreads();
    }
    if (t < nb) blksum[t] = tmp[t] - v;
}
__global__ void scan3_kernel(int* __restrict__ off, const int* __restrict__ blksum,
                             int n) {
    int i = blockIdx.x * blockDim.x + threadIdx.x;
    if (i < n) off[i] += blksum[i >> 10];
}
__global__ void fill3_kernel(const int* __restrict__ s0, const int* __restrict__ d0,
                             const int* __restrict__ s1, const int* __restrict__ d1,
                             const int* __restrict__ s2, const int* __restrict__ d2,
                             const int* __restrict__ off, int* __restrict__ cur,
                             int* __restrict__ srcs, int E, int N) {
    int i = blockIdx.x * blockDim.x + threadIdx.x;
    if (i >= 3 * E) return;
    int s, slot;
    if (i < E) { s = s0[i]; slot = d0[i]; }
    else if (i < 2 * E) { s = s1[i - E]; slot = N + d1[i - E]; }
    else { s = s2[i - 2 * E]; slot = 2 * N + d2[i - 2 * E]; }
    int p = off[slot] + atomicAdd(&cur[slot], 1);
    srcs[p] = s;
}

// ---------- fused single-pass online-softmax gather, 2-deep pipelined ----------
__global__ __launch_bounds__(256) void gat_gather_kernel(
    const int* __restrict__ off, const int* __restrict__ cnt,
    const int* __restrict__ srcs,
    const float* __restrict__ es, const float* __restrict__ ed,
    const float* __restrict__ ab, const u16* __restrict__ Wh,
    u16* __restrict__ out, float coeff, int accum, int base, int n) {
    int wid = (blockIdx.x * blockDim.x + threadIdx.x) >> 6;
    if (wid >= n) return;
    int lane = threadIdx.x & 63;
    int o = lane * 4, hh = lane >> 3;
    int start = off[base + wid], deg = cnt[base + wid];
    float edv = ed[wid * 8 + hh] + ab[hh];
    float m = -1e30f, psum = 0.f;
    float ax = 0.f, ay = 0.f, az = 0.f, aw = 0.f;
    if (deg > 0) {
        int sP = srcs[start];
        int sN = (deg > 1) ? srcs[start + 1] : sP;
        float rawP = es[sP * 8 + hh];
        ushort4 wP = *(const ushort4*)(Wh + (size_t)sP * FEATS + o);
        for (int j = 0; j < deg; ++j) {
            // prefetch for j+1 (addresses known from previous iteration)
            int sNN = (j + 2 < deg) ? srcs[start + j + 2] : sN;
            float rawN = es[sN * 8 + hh];
            ushort4 wN = *(const ushort4*)(Wh + (size_t)sN * FEATS + o);
            // process edge j with values loaded one iteration ago
            float e = rawP + edv;
            e = e > 0.f ? e : ALPHA * e;
            float mn = fmaxf(m, e);
            float rr = exp2f((m - mn) * LOG2E);
            float pe = exp2f((e - mn) * LOG2E);
            psum = psum * rr + pe;
            ax = ax * rr + pe * b2f(wP.x);
            ay = ay * rr + pe * b2f(wP.y);
            az = az * rr + pe * b2f(wP.z);
            aw = aw * rr + pe * b2f(wP.w);
            m = mn;
            rawP = rawN; wP = wN; sN = sNN;
        }
    }
    float sc = (deg > 0) ? (coeff / psum) : 0.f;
    float rx = ax * sc, ry = ay * sc, rz = az * sc, rw = aw * sc;
    u16* op = out + (size_t)wid * FEATS + o;
    if (accum) {
        ushort4 prev = *(const ushort4*)op;
        rx += b2f(prev.x); ry += b2f(prev.y);
        rz += b2f(prev.z); rw += b2f(prev.w);
    }
    ushort4 r;
    r.x = f2b(rx); r.y = f2b(ry); r.z = f2b(rz); r.w = f2b(rw);
    *(ushort4*)op = r;
}

// ---------- GRU elementwise (bf16 gi/gh/hmix -> f32 out) ----------
__global__ void gru_ew_kernel(const u16* __restrict__ gi, const u16* __restrict__ gh,
                              const u16* __restrict__ hmix, float* __restrict__ out,
                              int rows, int row0) {
    int i = blockIdx.x * blockDim.x + threadIdx.x;
    if (i >= rows * 128) return;
    int r = i >> 7, j = (i & 127) * 2;
    const u16* gir = gi + (size_t)r * 768;
    const u16* ghr = gh + (size_t)r * 768;
    ushort2 ir = *(const ushort2*)(gir + j);
    ushort2 iz = *(const ushort2*)(gir + 256 + j);
    ushort2 in_ = *(const ushort2*)(gir + 512 + j);
    ushort2 hr = *(const ushort2*)(ghr + j);
    ushort2 hz = *(const ushort2*)(ghr + 256 + j);
    ushort2 hn = *(const ushort2*)(ghr + 512 + j);
    ushort2 hm = *(const ushort2*)(hmix + (size_t)(row0 + r) * FEATS + j);
    float2 res;
    {
        float rr = 1.f / (1.f + exp2f(-(b2f(ir.x) + b2f(hr.x)) * LOG2E));
        float zz = 1.f / (1.f + exp2f(-(b2f(iz.x) + b2f(hz.x)) * LOG2E));
        float nn = tanhf(b2f(in_.x) + rr * b2f(hn.x));
        res.x = (1.f - zz) * nn + zz * b2f(hm.x);
    }
    {
        float rr = 1.f / (1.f + exp2f(-(b2f(ir.y) + b2f(hr.y)) * LOG2E));
        float zz = 1.f / (1.f + exp2f(-(b2f(iz.y) + b2f(hz.y)) * LOG2E));
        float nn = tanhf(b2f(in_.y) + rr * b2f(hn.y));
        res.y = (1.f - zz) * nn + zz * b2f(hm.y);
    }
    *(float2*)(out + (size_t)(row0 + r) * FEATS + j) = res;
}

// ---------- launch ----------
extern "C" void kernel_launch(void* const* d_in, const int* in_sizes, int n_in,
                              void* d_out, int out_size, void* d_ws, size_t ws_size,
                              hipStream_t stream) {
    const float* h        = (const float*)d_in[0];
    const float* hp_cnt   = (const float*)d_in[1];
    const float* hp_sup   = (const float*)d_in[2];
    const float* hp_dst   = (const float*)d_in[3];
    const float* W_gat    = (const float*)d_in[4];
    const float* b_gat    = (const float*)d_in[5];
    const float* as_gat   = (const float*)d_in[6];
    const float* ad_gat   = (const float*)d_in[7];
    const float* ab_gat   = (const float*)d_in[8];
    const float* W_x      = (const float*)d_in[9];
    const float* b_x      = (const float*)d_in[10];
    const float* as_x     = (const float*)d_in[11];
    const float* ad_x     = (const float*)d_in[12];
    const float* ab_x     = (const float*)d_in[13];
    const float* W_ih     = (const float*)d_in[14];
    const float* W_hh     = (const float*)d_in[15];
    const float* b_ih     = (const float*)d_in[16];
    const float* b_hh     = (const float*)d_in[17];
    const int* e_src      = (const int*)d_in[18];
    const int* e_dst      = (const int*)d_in[19];
    const int* ec_src     = (const int*)d_in[20];
    const int* ec_dst     = (const int*)d_in[21];
    const int* es_src     = (const int*)d_in[22];
    const int* es_dst     = (const int*)d_in[23];

    const int N = in_sizes[0] / FEATS;
    const int E = in_sizes[18];
    const int N8 = N * HEADS;
    const int N3 = 3 * N;
    const int NBLK3 = (N3 + 1023) / 1024;

    char* ws = (char*)d_ws;
    size_t p = 0;
    u16* WhS   = (u16*)(ws + p); p += (size_t)N * FEATS * 2;
    u16* WhD   = (u16*)(ws + p); p += (size_t)N * FEATS * 2;
    u16* xb    = (u16*)(ws + p); p += (size_t)N * FEATS * 2;
    u16* hmixb = (u16*)(ws + p); p += (size_t)N * FEATS * 2;
    float* esb = (float*)(ws + p); p += (size_t)N8 * 4;
    float* edb = (float*)(ws + p); p += (size_t)N8 * 4;
    int* cnt3  = (int*)(ws + p); p += (size_t)N3 * 4;
    int* off3  = (int*)(ws + p); p += (size_t)N3 * 4;
    int* cur3  = (int*)(ws + p); p += (size_t)N3 * 4;
    int* blks  = (int*)(ws + p); p += 1024;
    int* srcs3 = (int*)(ws + p); p += (size_t)3 * E * 4;
    u16* Bgat  = (u16*)(ws + p); p += 65536 * 2;
    u16* Bx    = (u16*)(ws + p); p += 65536 * 2;
    u16* Bih   = (u16*)(ws + p); p += 196608 * 2;
    u16* Bhh   = (u16*)(ws + p); p += 196608 * 2;
    const int CH = 16384;
    u16* giB   = (u16*)(ws + p); p += (size_t)CH * 768 * 2;
    u16* ghB   = (u16*)(ws + p); p += (size_t)CH * 768 * 2;

    const dim3 blk(256);
    const dim3 gProj((N + 127) / 128, FEATS / 128);
    const int gN8 = (N8 + 255) / 256;
    const int g3E = (3 * E + 255) / 256;
    const int gGather = (N * 64 + 255) / 256;

    // ---- weight prep + batched CSR build (independent of GEMMs) ----
    prep_kernel<<<2048, blk, 0, stream>>>(W_gat, W_x, W_ih, W_hh, Bgat, Bx, Bih, Bhh);
    hipMemsetAsync(cnt3, 0, (size_t)N3 * 4, stream);
    hipMemsetAsync(cur3, 0, (size_t)N3 * 4, stream);
    count3_kernel<<<g3E, blk, 0, stream>>>(e_dst, ec_dst, es_dst, cnt3, E, N);
    scan1_kernel<<<NBLK3, blk, 0, stream>>>(cnt3, off3, blks, N3);
    scan2_kernel<<<1, blk, 0, stream>>>(blks, NBLK3);
    scan3_kernel<<<(N3 + 255) / 256, blk, 0, stream>>>(off3, blks, N3);
    fill3_kernel<<<g3E, blk, 0, stream>>>(e_src, e_dst, ec_src, ec_dst, es_src, es_dst,
                                          off3, cur3, srcs3, E, N);

    // ---- GAT1: intra-turn on h ----
    gemm_mfma<1><<<gProj, blk, 0, stream>>>(h, Bgat, b_gat, WhS, N, FEATS);
    esed_kernel<1, 1><<<gN8, blk, 0, stream>>>(WhS, WhS, as_gat, ad_gat, esb, edb, N);
    gat_gather_kernel<<<gGather, blk, 0, stream>>>(off3, cnt3, srcs3, esb, edb,
                                                   ab_gat, WhS, xb, 1.0f, 0, 0, N);

    // ---- GAT2: counter (hp_counter -> hp_dst) ----
    gemm_mfma<1><<<gProj, blk, 0, stream>>>(hp_cnt, Bx, b_x, WhS, N, FEATS);
    gemm_mfma<1><<<gProj, blk, 0, stream>>>(hp_dst, Bx, b_x, WhD, N, FEATS);
    esed_kernel<1, 1><<<gN8, blk, 0, stream>>>(WhS, WhD, as_x, ad_x, esb, edb, N);
    gat_gather_kernel<<<gGather, blk, 0, stream>>>(off3, cnt3, srcs3, esb, edb,
                                                   ab_x, WhS, hmixb, 0.5f, 0, N, N);

    // ---- GAT3: support (hp_support -> hp_dst); ed (from hp_dst) unchanged ----
    gemm_mfma<1><<<gProj, blk, 0, stream>>>(hp_sup, Bx, b_x, WhS, N, FEATS);
    esed_kernel<1, 0><<<gN8, blk, 0, stream>>>(WhS, nullptr, as_x, nullptr, esb, nullptr, N);
    gat_gather_kernel<<<gGather, blk, 0, stream>>>(off3, cnt3, srcs3, esb, edb,
                                                   ab_x, WhS, hmixb, 0.5f, 1, 2 * N, N);

    // ---- GRU, chunked ----
    for (int row0 = 0; row0 < N; row0 += CH) {
        int rows = min(CH, N - row0);
        dim3 gG((rows + 127) / 128, 768 / 128);
        gemm_mfma<0><<<gG, blk, 0, stream>>>(xb + (size_t)row0 * FEATS, Bih, b_ih,
                                             giB, rows, 768);
        gemm_mfma<0><<<gG, blk, 0, stream>>>(hmixb + (size_t)row0 * FEATS, Bhh, b_hh,
                                             ghB, rows, 768);
        int gEw = (rows * 128 + 255) / 256;
        gru_ew_kernel<<<gEw, blk, 0, stream>>>(giB, ghB, hmixb, (float*)d_out, rows, row0);
    }
}

// Round 6
// 581.935 us; speedup vs baseline: 10.8015x; 1.1140x over previous
//
#include <hip/hip_runtime.h>
#include <math.h>

#define ALPHA 0.2f
#define LOG2E 1.44269504088896f

constexpr int FEATS = 256;   // NFEATS == NHIDS == K for every GEMM
constexpr int HEADS = 8;

typedef unsigned short u16;
typedef __attribute__((ext_vector_type(8))) short bf16x8;
typedef __attribute__((ext_vector_type(4))) float f32x4;

// ---------- bf16 helpers ----------
__device__ __forceinline__ u16 f2b(float f) {            // RNE
    unsigned u = __float_as_uint(f);
    u += 0x7FFF + ((u >> 16) & 1);
    return (u16)(u >> 16);
}
__device__ __forceinline__ float b2f(u16 x) {
    return __uint_as_float(((unsigned)x) << 16);
}
__device__ __forceinline__ unsigned pk2(float lo, float hi) {
    return __builtin_amdgcn_perm(__float_as_uint(hi), __float_as_uint(lo), 0x07060302u);
}
__device__ __forceinline__ void gload16(const void* g, void* l) {
    __builtin_amdgcn_global_load_lds(
        (const __attribute__((address_space(1))) unsigned int*)g,
        (__attribute__((address_space(3))) unsigned int*)l, 16, 0, 0);
}

// ---------- merged 4-way projection GEMM (A fp32, staged raw, cvt at frag load) ----
// seg 0: h@Bgat -> Wh1; 1: hp_cnt@Bx -> WhC; 2: hp_dst@Bx -> WhD; 3: hp_sup@Bx -> WhS3
__global__ __launch_bounds__(256) void proj4_kernel(
    const float* __restrict__ A0, const float* __restrict__ A1,
    const float* __restrict__ A2, const float* __restrict__ A3,
    const u16* __restrict__ Bg, const u16* __restrict__ Bx,
    const float* __restrict__ bg, const float* __restrict__ bx,
    u16* __restrict__ C0, u16* __restrict__ C1,
    u16* __restrict__ C2, u16* __restrict__ C3,
    int M, int NB) {
    __shared__ char As_raw[32768];  // 128 x 64 f32, swizzled
    __shared__ char Bs_raw[16384];  // 128 x 64 bf16, swizzled
    const int tid = threadIdx.x;
    const int lane = tid & 63;
    const int wid = tid >> 6;
    const int wr = wid >> 1, wc = wid & 1;
    const int seg = blockIdx.y / NB;
    const int bm = (blockIdx.y % NB) * 128;
    const int bn = blockIdx.x * 128;
    const float* A = (seg == 0) ? A0 : (seg == 1) ? A1 : (seg == 2) ? A2 : A3;
    const u16* B = (seg == 0) ? Bg : Bx;
    const float* bias = (seg == 0) ? bg : bx;
    u16* C = (seg == 0) ? C0 : (seg == 1) ? C1 : (seg == 2) ? C2 : C3;

    f32x4 acc[4][4];
#pragma unroll
    for (int m = 0; m < 4; ++m)
#pragma unroll
        for (int n = 0; n < 4; ++n) acc[m][n] = (f32x4)0.f;

    for (int kb = 0; kb < 4; ++kb) {
        const int k0g = kb * 64;
#pragma unroll
        for (int i = 0; i < 8; ++i) {
            int s = i * 256 + tid;          // f32 tile: 2048 16B slots
            int row = s >> 4, c16 = s & 15;
            int c32 = c16 >> 1, half = c16 & 1;
            int gr = min(bm + row, M - 1);
            int gcol = k0g + ((c32 ^ (row & 7)) * 8 + half * 4);
            gload16(A + (size_t)gr * 256 + gcol, As_raw + s * 16);
        }
#pragma unroll
        for (int i = 0; i < 4; ++i) {
            int s = i * 256 + tid;          // bf16 tile: 1024 slots
            int row = s >> 3, c16 = s & 7;
            int gcol = k0g + (c16 ^ (row & 7)) * 8;
            gload16(B + (size_t)(bn + row) * 256 + gcol, Bs_raw + s * 16);
        }
        __syncthreads();
#pragma unroll
        for (int kk = 0; kk < 2; ++kk) {
            const int ko = kk * 32 + (lane >> 4) * 8;
            const int kc = ko >> 3;
            bf16x8 af[4], bfr[4];
#pragma unroll
            for (int m = 0; m < 4; ++m) {
                int row = wr * 64 + m * 16 + (lane & 15);
                int byte = row * 256 + ((kc ^ (row & 7)) << 5);
                f32x4 lo = *(const f32x4*)(As_raw + byte);
                f32x4 hi = *(const f32x4*)(As_raw + byte + 16);
                union { unsigned u[4]; bf16x8 v; } cv;
                cv.u[0] = pk2(lo.x, lo.y); cv.u[1] = pk2(lo.z, lo.w);
                cv.u[2] = pk2(hi.x, hi.y); cv.u[3] = pk2(hi.z, hi.w);
                af[m] = cv.v;
            }
#pragma unroll
            for (int n = 0; n < 4; ++n) {
                int row = wc * 64 + n * 16 + (lane & 15);
                int byte = row * 128 + ((kc ^ (row & 7)) << 4);
                bfr[n] = *(const bf16x8*)(Bs_raw + byte);
            }
#pragma unroll
            for (int m = 0; m < 4; ++m)
#pragma unroll
                for (int n = 0; n < 4; ++n)
                    acc[m][n] = __builtin_amdgcn_mfma_f32_16x16x32_bf16(
                        af[m], bfr[n], acc[m][n], 0, 0, 0);
        }
        __syncthreads();
    }
#pragma unroll
    for (int m = 0; m < 4; ++m) {
#pragma unroll
        for (int j = 0; j < 4; ++j) {
            int gr = bm + wr * 64 + m * 16 + (lane >> 4) * 4 + j;
            if (gr < M) {
#pragma unroll
                for (int n = 0; n < 4; ++n) {
                    int gc = bn + wc * 64 + n * 16 + (lane & 15);
                    C[(size_t)gr * 256 + gc] = f2b(acc[m][n][j] + bias[gc]);
                }
            }
        }
    }
}

// ---------- weight prep ----------
// Bgat/Bx: [256][256], B[h*32+d][f] = W[h][f][d].
// Bihr/Bhhr: reordered [768][256]: c = q*48+g*16+jl  <->  orig row g*256+q*16+jl.
__global__ void prep_kernel(const float* __restrict__ W_gat, const float* __restrict__ W_x,
                            const float* __restrict__ W_ih, const float* __restrict__ W_hh,
                            u16* __restrict__ Bgat, u16* __restrict__ Bx,
                            u16* __restrict__ Bihr, u16* __restrict__ Bhhr) {
    int i = blockIdx.x * 256 + threadIdx.x;   // [0, 524288)
    if (i < 131072) {
        int j = i & 65535;
        int n = j >> 8, f = j & 255;
        int h2 = n >> 5, d = n & 31;
        const float* W = (i < 65536) ? W_gat : W_x;
        u16* Bt = (i < 65536) ? Bgat : Bx;
        Bt[j] = f2b(W[(h2 * 256 + f) * 32 + d]);
    } else {
        int x = i - 131072;                   // [0, 393216): two 196608 halves
        int lin = (x < 196608) ? x : x - 196608;
        int c = lin >> 8, k = lin & 255;
        int q = c / 48, rr = c - q * 48;
        int g = rr >> 4, jl = rr & 15;
        int orig = (g * 256 + q * 16 + jl) * 256 + k;
        if (x < 196608) Bihr[lin] = f2b(W_ih[orig]);
        else            Bhhr[lin] = f2b(W_hh[orig]);
    }
}

// ---------- merged es/ed (outputs pre-scaled by LOG2E) ----------
__global__ void esed_all_kernel(
    const u16* __restrict__ Wh1, const u16* __restrict__ WhC,
    const u16* __restrict__ WhD, const u16* __restrict__ WhS3,
    const float* __restrict__ as_g, const float* __restrict__ ad_g,
    const float* __restrict__ as_x, const float* __restrict__ ad_x,
    float* __restrict__ es1, float* __restrict__ ed1,
    float* __restrict__ esC, float* __restrict__ edD,
    float* __restrict__ esS, int n) {
    int idx = blockIdx.x * blockDim.x + threadIdx.x;
    if (idx >= n * 8) return;
    int node = idx >> 3, hh = idx & 7;
    float s1 = 0.f, d1 = 0.f, sC = 0.f, dD = 0.f, sS = 0.f;
#pragma unroll
    for (int i = 0; i < 8; ++i) {
        const float4 wsg = *(const float4*)(as_g + hh * 32 + i * 4);
        const float4 wdg = *(const float4*)(ad_g + hh * 32 + i * 4);
        const float4 wsx = *(const float4*)(as_x + hh * 32 + i * 4);
        const float4 wdx = *(const float4*)(ad_x + hh * 32 + i * 4);
        ushort4 v1 = *(const ushort4*)(Wh1 + (size_t)node * FEATS + hh * 32 + i * 4);
        ushort4 vC = *(const ushort4*)(WhC + (size_t)node * FEATS + hh * 32 + i * 4);
        ushort4 vD = *(const ushort4*)(WhD + (size_t)node * FEATS + hh * 32 + i * 4);
        ushort4 vS = *(const ushort4*)(WhS3 + (size_t)node * FEATS + hh * 32 + i * 4);
        s1 += b2f(v1.x) * wsg.x + b2f(v1.y) * wsg.y + b2f(v1.z) * wsg.z + b2f(v1.w) * wsg.w;
        d1 += b2f(v1.x) * wdg.x + b2f(v1.y) * wdg.y + b2f(v1.z) * wdg.z + b2f(v1.w) * wdg.w;
        sC += b2f(vC.x) * wsx.x + b2f(vC.y) * wsx.y + b2f(vC.z) * wsx.z + b2f(vC.w) * wsx.w;
        dD += b2f(vD.x) * wdx.x + b2f(vD.y) * wdx.y + b2f(vD.z) * wdx.z + b2f(vD.w) * wdx.w;
        sS += b2f(vS.x) * wsx.x + b2f(vS.y) * wsx.y + b2f(vS.z) * wsx.z + b2f(vS.w) * wsx.w;
    }
    es1[idx] = s1 * LOG2E; ed1[idx] = d1 * LOG2E;
    esC[idx] = sC * LOG2E; edD[idx] = dD * LOG2E;
    esS[idx] = sS * LOG2E;
}

// ---------- batched CSR build over 3 edge lists ----------
__global__ void count3_kernel(const int* __restrict__ d0, const int* __restrict__ d1,
                              const int* __restrict__ d2, int* __restrict__ cnt,
                              int E, int N) {
    int i = blockIdx.x * blockDim.x + threadIdx.x;
    if (i >= 3 * E) return;
    if (i < E) atomicAdd(&cnt[d0[i]], 1);
    else if (i < 2 * E) atomicAdd(&cnt[N + d1[i - E]], 1);
    else atomicAdd(&cnt[2 * N + d2[i - 2 * E]], 1);
}
__global__ void scan1_kernel(const int* __restrict__ cnt, int* __restrict__ off,
                             int* __restrict__ blksum, int n) {
    __shared__ int tmp[256];
    int t = threadIdx.x;
    int base = blockIdx.x * 1024 + t * 4;
    int v[4];
#pragma unroll
    for (int k = 0; k < 4; ++k) v[k] = (base + k < n) ? cnt[base + k] : 0;
    int s = v[0] + v[1] + v[2] + v[3];
    tmp[t] = s;
    __syncthreads();
    for (int st = 1; st < 256; st <<= 1) {
        int add = (t >= st) ? tmp[t - st] : 0;
        __syncthreads();
        tmp[t] += add;
        __syncthreads();
    }
    int ex = tmp[t] - s;
#pragma unroll
    for (int k = 0; k < 4; ++k) {
        if (base + k < n) off[base + k] = ex;
        ex += v[k];
    }
    if (t == 255) blksum[blockIdx.x] = tmp[255];
}
__global__ void scan2_kernel(int* __restrict__ blksum, int nb) {
    __shared__ int tmp[256];
    int t = threadIdx.x;
    int v = (t < nb) ? blksum[t] : 0;
    tmp[t] = v;
    __syncthreads();
    for (int s = 1; s < 256; s <<= 1) {
        int add = (t >= s) ? tmp[t - s] : 0;
        __syncthreads();
        tmp[t] += add;
        __syncthreads();
    }
    if (t < nb) blksum[t] = tmp[t] - v;
}
// off += blkpfx; cur = off  (fill consumes cur via atomicAdd, gather keeps off)
__global__ void scan3_kernel(int* __restrict__ off, int* __restrict__ cur,
                             const int* __restrict__ blksum, int n) {
    int i = blockIdx.x * blockDim.x + threadIdx.x;
    if (i < n) {
        int v = off[i] + blksum[i >> 10];
        off[i] = v;
        cur[i] = v;
    }
}
__global__ void fill3_kernel(const int* __restrict__ s0, const int* __restrict__ d0,
                             const int* __restrict__ s1, const int* __restrict__ d1,
                             const int* __restrict__ s2, const int* __restrict__ d2,
                             int* __restrict__ cur, int* __restrict__ srcs, int E, int N) {
    int i = blockIdx.x * blockDim.x + threadIdx.x;
    if (i >= 3 * E) return;
    int s, slot;
    if (i < E) { s = s0[i]; slot = d0[i]; }
    else if (i < 2 * E) { s = s1[i - E]; slot = N + d1[i - E]; }
    else { s = s2[i - 2 * E]; slot = 2 * N + d2[i - 2 * E]; }
    int p = atomicAdd(&cur[slot], 1);
    srcs[p] = s;
}

// ---------- online-softmax segment walk (base-2 domain), 2-deep pipelined ----------
__device__ __forceinline__ void run_seg(
    const int* __restrict__ srcs, int start, int deg,
    const float* __restrict__ es, const u16* __restrict__ Wh,
    float edv, int o, int hh,
    float& psum, float4& a) {
    float m = -1e30f;
    psum = 0.f;
    a = make_float4(0.f, 0.f, 0.f, 0.f);
    if (deg <= 0) return;
    int sP = srcs[start];
    int sN = (deg > 1) ? srcs[start + 1] : sP;
    float rawP = es[sP * 8 + hh];
    ushort4 wP = *(const ushort4*)(Wh + (size_t)sP * FEATS + o);
    for (int j = 0; j < deg; ++j) {
        int sNN = (j + 2 < deg) ? srcs[start + j + 2] : sN;
        float rawN = es[sN * 8 + hh];
        ushort4 wN = *(const ushort4*)(Wh + (size_t)sN * FEATS + o);
        float e = rawP + edv;                  // already log2-scaled
        e = e > 0.f ? e : ALPHA * e;
        float mn = fmaxf(m, e);
        float rr = exp2f(m - mn);
        float pe = exp2f(e - mn);
        psum = psum * rr + pe;
        a.x = a.x * rr + pe * b2f(wP.x);
        a.y = a.y * rr + pe * b2f(wP.y);
        a.z = a.z * rr + pe * b2f(wP.z);
        a.w = a.w * rr + pe * b2f(wP.w);
        m = mn;
        rawP = rawN; wP = wN; sN = sNN;
    }
}

// ---------- one launch: GAT1 waves [0,N), fused GAT2+GAT3 waves [N,2N) ----------
__global__ __launch_bounds__(256) void gather_all_kernel(
    const int* __restrict__ off, const int* __restrict__ cnt,
    const int* __restrict__ srcs,
    const float* __restrict__ es1, const float* __restrict__ ed1,
    const float* __restrict__ esC, const float* __restrict__ edD,
    const float* __restrict__ esS,
    const float* __restrict__ ab_g, const float* __restrict__ ab_x,
    const u16* __restrict__ Wh1, const u16* __restrict__ WhC,
    const u16* __restrict__ WhS3,
    u16* __restrict__ xb, u16* __restrict__ hmixb, int N) {
    int gwid = (blockIdx.x * blockDim.x + threadIdx.x) >> 6;
    if (gwid >= 2 * N) return;
    int lane = threadIdx.x & 63;
    int o = lane * 4, hh = lane >> 3;
    if (gwid < N) {
        int node = gwid;
        float edv = ed1[node * 8 + hh] + ab_g[hh] * LOG2E;
        float psum; float4 a;
        run_seg(srcs, off[node], cnt[node], es1, Wh1, edv, o, hh, psum, a);
        float sc = (cnt[node] > 0) ? (1.0f / psum) : 0.f;
        ushort4 r;
        r.x = f2b(a.x * sc); r.y = f2b(a.y * sc);
        r.z = f2b(a.z * sc); r.w = f2b(a.w * sc);
        *(ushort4*)(xb + (size_t)node * FEATS + o) = r;
    } else {
        int node = gwid - N;
        float edv = edD[node * 8 + hh] + ab_x[hh] * LOG2E;
        float psum2; float4 a2;
        run_seg(srcs, off[N + node], cnt[N + node], esC, WhC, edv, o, hh, psum2, a2);
        float sc2 = (cnt[N + node] > 0) ? (0.5f / psum2) : 0.f;
        float psum3; float4 a3;
        run_seg(srcs, off[2 * N + node], cnt[2 * N + node], esS, WhS3, edv, o, hh, psum3, a3);
        float sc3 = (cnt[2 * N + node] > 0) ? (0.5f / psum3) : 0.f;
        ushort4 r;
        r.x = f2b(a2.x * sc2 + a3.x * sc3);
        r.y = f2b(a2.y * sc2 + a3.y * sc3);
        r.z = f2b(a2.z * sc2 + a3.z * sc3);
        r.w = f2b(a2.w * sc2 + a3.w * sc3);
        *(ushort4*)(hmixb + (size_t)node * FEATS + o) = r;
    }
}

// ---------- fully-fused GRU: both GEMMs + gates in one kernel ----------
// Block: 128 rows x 96 reordered cols (q in {2bt+wc}: 16 j's x 3 gates, g=n-frag).
__device__ __forceinline__ void gemm_pass_gru(
    const u16* __restrict__ A, const u16* __restrict__ B,
    int bm, int bt, int M, char* As, char* Bs,
    int tid, int lane, int wr, int wc, f32x4 (&acc)[4][3]) {
    for (int kb = 0; kb < 4; ++kb) {
        const int k0g = kb * 64;
#pragma unroll
        for (int i = 0; i < 4; ++i) {
            int s = i * 256 + tid;          // A: 128x64 bf16 = 1024 slots
            int row = s >> 3, c16 = s & 7;
            int gr = min(bm + row, M - 1);
            int gcol = k0g + (c16 ^ (row & 7)) * 8;
            gload16(A + (size_t)gr * 256 + gcol, As + s * 16);
        }
#pragma unroll
        for (int i = 0; i < 3; ++i) {
            int s = i * 256 + tid;          // B: 96x64 bf16 = 768 slots
            int row = s >> 3, c16 = s & 7;
            int gcol = k0g + (c16 ^ (row & 7)) * 8;
            gload16(B + (size_t)(bt * 96 + row) * 256 + gcol, Bs + s * 16);
        }
        __syncthreads();
#pragma unroll
        for (int kk = 0; kk < 2; ++kk) {
            const int ko = kk * 32 + (lane >> 4) * 8;
            const int kc = ko >> 3;
            bf16x8 af[4], bfr[3];
#pragma unroll
            for (int m = 0; m < 4; ++m) {
                int row = wr * 64 + m * 16 + (lane & 15);
                af[m] = *(const bf16x8*)(As + row * 128 + ((kc ^ (row & 7)) << 4));
            }
#pragma unroll
            for (int n = 0; n < 3; ++n) {
                int row = wc * 48 + n * 16 + (lane & 15);
                bfr[n] = *(const bf16x8*)(Bs + row * 128 + ((kc ^ (row & 7)) << 4));
            }
#pragma unroll
            for (int m = 0; m < 4; ++m)
#pragma unroll
                for (int n = 0; n < 3; ++n)
                    acc[m][n] = __builtin_amdgcn_mfma_f32_16x16x32_bf16(
                        af[m], bfr[n], acc[m][n], 0, 0, 0);
        }
        __syncthreads();
    }
}

__global__ __launch_bounds__(256) void gru_fused_kernel(
    const u16* __restrict__ xb, const u16* __restrict__ hmixb,
    const u16* __restrict__ Bihr, const u16* __restrict__ Bhhr,
    const float* __restrict__ b_ih, const float* __restrict__ b_hh,
    float* __restrict__ out, int M) {
    __shared__ char As[16384];
    __shared__ char Bs[12288];
    const int tid = threadIdx.x;
    const int lane = tid & 63;
    const int wid = tid >> 6;
    const int wr = wid >> 1, wc = wid & 1;
    const int bt = blockIdx.x;          // 0..7
    const int bm = blockIdx.y * 128;

    f32x4 agi[4][3], agh[4][3];
#pragma unroll
    for (int m = 0; m < 4; ++m)
#pragma unroll
        for (int n = 0; n < 3; ++n) { agi[m][n] = (f32x4)0.f; agh[m][n] = (f32x4)0.f; }

    gemm_pass_gru(xb, Bihr, bm, bt, M, As, Bs, tid, lane, wr, wc, agi);
    gemm_pass_gru(hmixb, Bhhr, bm, bt, M, As, Bs, tid, lane, wr, wc, agh);

    // epilogue: lane owns j = q*16 + (lane&15), q = bt*2+wc; gate g = n-frag.
    const int j = (bt * 2 + wc) * 16 + (lane & 15);
    const float bir = b_ih[j], biz = b_ih[256 + j], bin = b_ih[512 + j];
    const float bhr = b_hh[j], bhz = b_hh[256 + j], bhn = b_hh[512 + j];
#pragma unroll
    for (int m = 0; m < 4; ++m) {
#pragma unroll
        for (int jj = 0; jj < 4; ++jj) {
            int row = bm + wr * 64 + m * 16 + (lane >> 4) * 4 + jj;
            if (row < M) {
                float gr_ = agi[m][0][jj] + bir + agh[m][0][jj] + bhr;
                float gz_ = agi[m][1][jj] + biz + agh[m][1][jj] + bhz;
                float rr = 1.f / (1.f + exp2f(-gr_ * LOG2E));
                float zz = 1.f / (1.f + exp2f(-gz_ * LOG2E));
                float nn = tanhf(agi[m][2][jj] + bin + rr * (agh[m][2][jj] + bhn));
                float hm = b2f(hmixb[(size_t)row * 256 + j]);
                out[(size_t)row * 256 + j] = (1.f - zz) * nn + zz * hm;
            }
        }
    }
}

// ---------- launch ----------
extern "C" void kernel_launch(void* const* d_in, const int* in_sizes, int n_in,
                              void* d_out, int out_size, void* d_ws, size_t ws_size,
                              hipStream_t stream) {
    const float* h        = (const float*)d_in[0];
    const float* hp_cnt   = (const float*)d_in[1];
    const float* hp_sup   = (const float*)d_in[2];
    const float* hp_dst   = (const float*)d_in[3];
    const float* W_gat    = (const float*)d_in[4];
    const float* b_gat    = (const float*)d_in[5];
    const float* as_gat   = (const float*)d_in[6];
    const float* ad_gat   = (const float*)d_in[7];
    const float* ab_gat   = (const float*)d_in[8];
    const float* W_x      = (const float*)d_in[9];
    const float* b_x      = (const float*)d_in[10];
    const float* as_x     = (const float*)d_in[11];
    const float* ad_x     = (const float*)d_in[12];
    const float* ab_x     = (const float*)d_in[13];
    const float* W_ih     = (const float*)d_in[14];
    const float* W_hh     = (const float*)d_in[15];
    const float* b_ih     = (const float*)d_in[16];
    const float* b_hh     = (const float*)d_in[17];
    const int* e_src      = (const int*)d_in[18];
    const int* e_dst      = (const int*)d_in[19];
    const int* ec_src     = (const int*)d_in[20];
    const int* ec_dst     = (const int*)d_in[21];
    const int* es_src     = (const int*)d_in[22];
    const int* es_dst     = (const int*)d_in[23];

    const int N = in_sizes[0] / FEATS;
    const int E = in_sizes[18];
    const int N8 = N * HEADS;
    const int N3 = 3 * N;
    const int NBLK3 = (N3 + 1023) / 1024;
    const int NB128 = (N + 127) / 128;

    char* ws = (char*)d_ws;
    size_t p = 0;
    u16* Wh1   = (u16*)(ws + p); p += (size_t)N * FEATS * 2;
    u16* WhC   = (u16*)(ws + p); p += (size_t)N * FEATS * 2;
    u16* WhD   = (u16*)(ws + p); p += (size_t)N * FEATS * 2;
    u16* WhS3  = (u16*)(ws + p); p += (size_t)N * FEATS * 2;
    u16* xb    = (u16*)(ws + p); p += (size_t)N * FEATS * 2;
    u16* hmixb = (u16*)(ws + p); p += (size_t)N * FEATS * 2;
    float* es1 = (float*)(ws + p); p += (size_t)N8 * 4;
    float* ed1 = (float*)(ws + p); p += (size_t)N8 * 4;
    float* esC = (float*)(ws + p); p += (size_t)N8 * 4;
    float* edD = (float*)(ws + p); p += (size_t)N8 * 4;
    float* esS = (float*)(ws + p); p += (size_t)N8 * 4;
    int* cnt3  = (int*)(ws + p); p += (size_t)N3 * 4;
    int* off3  = (int*)(ws + p); p += (size_t)N3 * 4;
    int* cur3  = (int*)(ws + p); p += (size_t)N3 * 4;
    int* blks  = (int*)(ws + p); p += 1024;
    int* srcs3 = (int*)(ws + p); p += (size_t)3 * E * 4;
    u16* Bgat  = (u16*)(ws + p); p += 65536 * 2;
    u16* Bx    = (u16*)(ws + p); p += 65536 * 2;
    u16* Bihr  = (u16*)(ws + p); p += 196608 * 2;
    u16* Bhhr  = (u16*)(ws + p); p += 196608 * 2;

    const dim3 blk(256);
    const int gN8 = (N8 + 255) / 256;
    const int g3E = (3 * E + 255) / 256;

    // weight prep + CSR build
    prep_kernel<<<2048, blk, 0, stream>>>(W_gat, W_x, W_ih, W_hh, Bgat, Bx, Bihr, Bhhr);
    hipMemsetAsync(cnt3, 0, (size_t)N3 * 4, stream);
    count3_kernel<<<g3E, blk, 0, stream>>>(e_dst, ec_dst, es_dst, cnt3, E, N);
    scan1_kernel<<<NBLK3, blk, 0, stream>>>(cnt3, off3, blks, N3);
    scan2_kernel<<<1, blk, 0, stream>>>(blks, NBLK3);
    scan3_kernel<<<(N3 + 255) / 256, blk, 0, stream>>>(off3, cur3, blks, N3);
    fill3_kernel<<<g3E, blk, 0, stream>>>(e_src, e_dst, ec_src, ec_dst, es_src, es_dst,
                                          cur3, srcs3, E, N);

    // 4 projections in one launch
    proj4_kernel<<<dim3(2, 4 * NB128), blk, 0, stream>>>(
        h, hp_cnt, hp_dst, hp_sup, Bgat, Bx, b_gat, b_x,
        Wh1, WhC, WhD, WhS3, N, NB128);

    // merged es/ed
    esed_all_kernel<<<gN8, blk, 0, stream>>>(Wh1, WhC, WhD, WhS3,
                                             as_gat, ad_gat, as_x, ad_x,
                                             es1, ed1, esC, edD, esS, N);

    // all three GATs in one launch (2N waves)
    gather_all_kernel<<<(2 * N * 64 + 255) / 256, blk, 0, stream>>>(
        off3, cnt3, srcs3, es1, ed1, esC, edD, esS, ab_gat, ab_x,
        Wh1, WhC, WhS3, xb, hmixb, N);

    // fused GRU (both GEMMs + gates)
    gru_fused_kernel<<<dim3(8, NB128), blk, 0, stream>>>(
        xb, hmixb, Bihr, Bhhr, b_ih, b_hh, (float*)d_out, N);
}